// Round 10
// baseline (778.499 us; speedup 1.0000x reference)
//
#include <hip/hip_runtime.h>

// GMAN pipeline, fully fused, MFMA edition. support = I -> per-block token GEMMs.
// B=64, P=Q=12, N=1024, D=64. Output [B,Q,N] fp32.
//
// R21 = R20 (467us: direct-x, FRX staged, 5 barriers/p-step, no spill) with
// the packed hi|lo activation format replaced by SPLIT bf16 PLANES.
// R20 post-mortem: VALUBusy 44.9% vs MfmaUtil 23.4% -> VALU stream dominates.
// 48 lda_packed calls/p-step x 8 v_perm = 384 v_perm just to de-interleave
// the packed format for MFMA. Plane layout:
//  - hi plane + lo plane, u16[64 tok][64 col] each (8KB; 16KB/buffer = same
//    LDS as packed; total stays 80KB -> 2 blocks/CU).
//  - A-frag (row m, 8 consecutive k) = ONE aligned ds_read_b128 per plane,
//    fed to MFMA directly. ZERO v_perm.
//  - granule swizzle pos=(col>>3)^(row&7): frag reads uniform over 8
//    positions (conflict-free); scalar/b16 writes ~4-way worst (1-cyc ops).
//  - head GEMV: lane reads position p^(l&7) -> cols p*8.. (uniform Wo2 row,
//    conflict-free read).
// Tripwires: WRITE_SIZE ~126MB flat (no spill); VGPR<=128.
// Predicted: VALUBusy -> ~35, dur 467 -> ~415-440us.

#define NB 1024

typedef float f32x4 __attribute__((ext_vector_type(4)));
typedef __bf16 bf16x8 __attribute__((ext_vector_type(8)));
typedef int i32x4 __attribute__((ext_vector_type(4)));
typedef unsigned int u32;
typedef unsigned short u16;

#define MFMA(a, b, c) __builtin_amdgcn_mfma_f32_16x16x32_bf16(a, b, c, 0, 0, 0)

__device__ __forceinline__ float fexp(float x) {
    return __builtin_amdgcn_exp2f(x * 1.44269504088896341f);
}
__device__ __forceinline__ float fsigmoid(float x) {
    return __builtin_amdgcn_rcpf(1.0f + fexp(-x));
}
__device__ __forceinline__ float ftanh(float x) {
    return 1.0f - 2.0f * __builtin_amdgcn_rcpf(1.0f + fexp(2.0f * x));
}

__device__ __forceinline__ float toF(u16 h) {
    return __builtin_bit_cast(float, (u32)h << 16);
}
// write v as bf16 hi/lo into the two planes at u16-offset a
__device__ __forceinline__ void wplane(u16* __restrict__ Ph, u16* __restrict__ Pl,
                                       int a, float v) {
    __bf16 h = (__bf16)v;
    Ph[a] = __builtin_bit_cast(u16, h);
    Pl[a] = __builtin_bit_cast(u16, (__bf16)(v - (float)h));
}

__device__ __forceinline__ bf16x8 ldfrag(const u16* p) {
    i32x4 t = *(const i32x4*)p;
    return __builtin_bit_cast(bf16x8, t);
}
// fragment load from an LDS-staged table (ds_read_b128)
__device__ __forceinline__ bf16x8 ldfragL(const u32* p) {
    i32x4 t = *(const i32x4*)p;
    return __builtin_bit_cast(bf16x8, t);
}
__device__ __forceinline__ void split8(f32x4 a0, f32x4 a1, bf16x8& hi, bf16x8& lo) {
    #pragma unroll
    for (int i = 0; i < 4; i++) {
        __bf16 h0 = (__bf16)a0[i]; hi[i] = h0;     lo[i] = (__bf16)(a0[i] - (float)h0);
        __bf16 h1 = (__bf16)a1[i]; hi[4 + i] = h1; lo[4 + i] = (__bf16)(a1[i] - (float)h1);
    }
}

// plane addressing (u16 units). Row = token, 64 cols, 8-col granules (16B).
// Granule position swizzled by row: pos = (col>>3) ^ (row&7).
__device__ __forceinline__ int pa(int tok, int c) {
    return tok * 64 + (((c >> 3) ^ (tok & 7)) << 3) + (c & 7);
}
// frag base: row m, k-window kk (multiple of 8) -> 16B-aligned
__device__ __forceinline__ int pfrag(int m, int kk) {
    return m * 64 + ((((kk) >> 3) ^ (m & 7)) << 3);
}

// ---------------- ws layout (dwords) ----------------
// 0      FR_G1 [wq][nt][ks][half][lane][8bf16] 16384 dw ; 16384 FR_G2
// 32768  FR_C1 [wq][ks][half][lane][8] 8192 dw ; 40960 FR_C2
// 49152  FR_XE Win2 ; 53248 FR_HD Wo1
// 57344  seB [nb(16)][w(4)][lane(64)][16] fp32 (b_in2 folded)  65536 dw
// 122880 teo [768][64] fp32

__device__ __forceinline__ void wsplit(float v, u16* dhi, u16* dlo) {
    __bf16 h = (__bf16)v;
    __bf16 l = (__bf16)(v - (float)h);
    *dhi = __builtin_bit_cast(u16, h);
    *dlo = __builtin_bit_cast(u16, l);
}

__global__ void prep_gates(const float* __restrict__ Wg1, const float* __restrict__ Wg2,
                           u16* __restrict__ fr) {
    int i = blockIdx.x * 256 + threadIdx.x;            // [0, 4096)
    if (i >= 4096) return;
    int layer = i >> 11, r = i & 2047;
    int w = r >> 9; r &= 511; int nt = r >> 8; r &= 255; int ks = r >> 6; int lane = r & 63;
    const float* Wg = layer ? Wg2 : Wg1;
    int n = lane & 15, q = lane >> 4;
    int col = nt ? (64 + w * 16 + n) : (w * 16 + n);
    u16* dst = fr + layer * 32768 + (((w * 2 + nt) * 4 + ks) * 2) * 512 + lane * 8;
    #pragma unroll
    for (int j = 0; j < 8; j++) {
        int k = ks * 32 + q * 8 + j;
        float v = Wg[k * 128 + col] + Wg[(k + 128) * 128 + col];
        wsplit(v, dst + j, dst + 512 + j);
    }
}

__global__ void prep_cand(const float* __restrict__ Wc1, const float* __restrict__ Wc2,
                          u16* __restrict__ fr) {
    int i = blockIdx.x * 256 + threadIdx.x;            // [0, 2048)
    if (i >= 2048) return;
    int layer = i >> 10, r = i & 1023;
    int w = r >> 8; r &= 255; int ks = r >> 6; int lane = r & 63;
    const float* Wc = layer ? Wc2 : Wc1;
    int n = lane & 15, q = lane >> 4;
    int col = w * 16 + n;
    u16* dst = fr + 65536 + layer * 16384 + ((w * 4 + ks) * 2) * 512 + lane * 8;
    #pragma unroll
    for (int j = 0; j < 8; j++) {
        int k = ks * 32 + q * 8 + j;
        float v = Wc[k * 64 + col] + Wc[(k + 128) * 64 + col];
        wsplit(v, dst + j, dst + 512 + j);
    }
}

__global__ void prep_small(const float* __restrict__ Win2, const float* __restrict__ Wo1,
                           u16* __restrict__ fr) {
    int i = blockIdx.x * 256 + threadIdx.x;            // [0, 1024)
    if (i >= 1024) return;
    int kind = i >> 9, r = i & 511;
    int w = r >> 7; r &= 127; int ks = r >> 6; int lane = r & 63;
    const float* W = kind ? Wo1 : Win2;
    int n = lane & 15, q = lane >> 4;
    int col = w * 16 + n;
    u16* dst = fr + 98304 + kind * 8192 + ((w * 2 + ks) * 2) * 512 + lane * 8;
    #pragma unroll
    for (int j = 0; j < 8; j++) {
        int k = ks * 32 + q * 8 + j;
        float v = W[k * 64 + col];
        wsplit(v, dst + j, dst + 512 + j);
    }
}

// se lane-ordered: n = nb*64 + mt*16 + q*4 + r, d = w*16+n16, l = q*16+n16
__global__ void prep_se(const float* __restrict__ SE, const float* __restrict__ W1,
                        const float* __restrict__ b1, const float* __restrict__ W2,
                        const float* __restrict__ b2, const float* __restrict__ bin2,
                        float* __restrict__ seB) {
    __shared__ float h[64];
    int n = blockIdx.x, d = threadIdx.x;
    float acc = b1[d];
    for (int k = 0; k < 64; k++) acc = fmaf(SE[n * 64 + k], W1[k * 64 + d], acc);
    h[d] = fmaxf(acc, 0.0f);
    __syncthreads();
    float acc2 = b2[d];
    for (int k = 0; k < 64; k++) acc2 = fmaf(h[k], W2[k * 64 + d], acc2);
    int nb = n >> 6, tok = n & 63;
    int mt = tok >> 4, q = (tok >> 2) & 3, r = tok & 3;
    int w = d >> 4, n16 = d & 15;
    seB[(((nb * 4 + w) * 64) + q * 16 + n16) * 16 + mt * 4 + r] = acc2 + bin2[d];
}

__global__ void prep_te(const int* __restrict__ TE, const float* __restrict__ W1,
                        const float* __restrict__ b1, const float* __restrict__ W2,
                        const float* __restrict__ b2, float* __restrict__ teo) {
    __shared__ float h[64];
    int bp = blockIdx.x;
    int b = bp / 12, p = bp - b * 12;
    int d = threadIdx.x;
    int dow = TE[(b * 24 + p) * 2 + 0];
    int tod = TE[(b * 24 + p) * 2 + 1];
    float v = W1[dow * 64 + d] + W1[(7 + tod) * 64 + d] + b1[d];
    h[d] = fmaxf(v, 0.0f);
    __syncthreads();
    float acc = b2[d];
    for (int k = 0; k < 64; k++) acc = fmaf(h[k], W2[k * 64 + d], acc);
    teo[bp * 64 + d] = acc;
}

// full GRU step, plane edition. Wave owns cols [16w,16w+16). Gate + cand
// fragments streamed from ws (L2-resident). RS separate planes (alias is
// spill-bait: R19). No soldv (R15 lesson).
__device__ __forceinline__ void gru_full(
    const u16* __restrict__ XINh, const u16* __restrict__ XINl,
    u16* __restrict__ Sh, u16* __restrict__ Sl,
    u16* __restrict__ RSh, u16* __restrict__ RSl,
    const u16* __restrict__ frG, const u16* __restrict__ frC,
    float bgr, float bgu, float bcc, int l, int col) {
    const int n16 = l & 15, q = l >> 4;
    f32x4 accR[4], accU[4], accC[4];
    #pragma unroll
    for (int mt = 0; mt < 4; mt++) {
        accR[mt] = (f32x4)0.0f; accU[mt] = (f32x4)0.0f; accC[mt] = (f32x4)0.0f;
    }
    // phase 1: ks 0..1 (XIN K-half): one A-frag feeds R+U+C
    #pragma unroll
    for (int ks = 0; ks < 2; ks++) {
        bf16x8 gRh = ldfrag(frG + (ks * 2 + 0) * 512 + l * 8);
        bf16x8 gRl = ldfrag(frG + (ks * 2 + 1) * 512 + l * 8);
        bf16x8 gUh = ldfrag(frG + (8 + ks * 2 + 0) * 512 + l * 8);
        bf16x8 gUl = ldfrag(frG + (8 + ks * 2 + 1) * 512 + l * 8);
        bf16x8 bhiC = ldfrag(frC + (ks * 2 + 0) * 512 + l * 8);
        bf16x8 bloC = ldfrag(frC + (ks * 2 + 1) * 512 + l * 8);
        const int kk = ks * 32 + q * 8;
        #pragma unroll
        for (int mt = 0; mt < 4; mt++) {
            const int fb = pfrag(mt * 16 + n16, kk);
            bf16x8 ahi = ldfrag(XINh + fb);
            bf16x8 alo = ldfrag(XINl + fb);
            accR[mt] = MFMA(ahi, gRh, accR[mt]);
            accR[mt] = MFMA(alo, gRh, accR[mt]);
            accR[mt] = MFMA(ahi, gRl, accR[mt]);
            accU[mt] = MFMA(ahi, gUh, accU[mt]);
            accU[mt] = MFMA(alo, gUh, accU[mt]);
            accU[mt] = MFMA(ahi, gUl, accU[mt]);
            accC[mt] = MFMA(ahi, bhiC, accC[mt]);
            accC[mt] = MFMA(alo, bhiC, accC[mt]);
            accC[mt] = MFMA(ahi, bloC, accC[mt]);
        }
    }
    // phase 2: ks 2..3 (S K-half): gates only
    #pragma unroll
    for (int ks = 2; ks < 4; ks++) {
        bf16x8 gRh = ldfrag(frG + (ks * 2 + 0) * 512 + l * 8);
        bf16x8 gRl = ldfrag(frG + (ks * 2 + 1) * 512 + l * 8);
        bf16x8 gUh = ldfrag(frG + (8 + ks * 2 + 0) * 512 + l * 8);
        bf16x8 gUl = ldfrag(frG + (8 + ks * 2 + 1) * 512 + l * 8);
        const int kk = (ks - 2) * 32 + q * 8;
        #pragma unroll
        for (int mt = 0; mt < 4; mt++) {
            const int fb = pfrag(mt * 16 + n16, kk);
            bf16x8 ahi = ldfrag(Sh + fb);
            bf16x8 alo = ldfrag(Sl + fb);
            accR[mt] = MFMA(ahi, gRh, accR[mt]);
            accR[mt] = MFMA(alo, gRh, accR[mt]);
            accR[mt] = MFMA(ahi, gRl, accR[mt]);
            accU[mt] = MFMA(ahi, gUh, accU[mt]);
            accU[mt] = MFMA(alo, gUh, accU[mt]);
            accU[mt] = MFMA(ahi, gUl, accU[mt]);
        }
    }
    // rs = sigmoid(r) * s (RS separate planes -> no barrier needed first)
    #pragma unroll
    for (int mt = 0; mt < 4; mt++)
        #pragma unroll
        for (int r = 0; r < 4; r++) {
            int tok = mt * 16 + q * 4 + r;
            int a = pa(tok, col);
            float sold = toF(Sh[a]) + toF(Sl[a]);
            wplane(RSh, RSl, a, fsigmoid(accR[mt][r] + bgr) * sold);
        }
    __syncthreads();   // rs visible
    // cand ks 2..3 (RS K-half)
    #pragma unroll
    for (int ks = 2; ks < 4; ks++) {
        bf16x8 bhi = ldfrag(frC + (ks * 2 + 0) * 512 + l * 8);
        bf16x8 blo = ldfrag(frC + (ks * 2 + 1) * 512 + l * 8);
        const int kk = (ks - 2) * 32 + q * 8;
        #pragma unroll
        for (int mt = 0; mt < 4; mt++) {
            const int fb = pfrag(mt * 16 + n16, kk);
            bf16x8 ahi = ldfrag(RSh + fb);
            bf16x8 alo = ldfrag(RSl + fb);
            accC[mt] = MFMA(ahi, bhi, accC[mt]);
            accC[mt] = MFMA(alo, bhi, accC[mt]);
            accC[mt] = MFMA(ahi, blo, accC[mt]);
        }
    }
    // state update (sold re-read from planes: same thread, same address)
    #pragma unroll
    for (int mt = 0; mt < 4; mt++)
        #pragma unroll
        for (int r = 0; r < 4; r++) {
            int tok = mt * 16 + q * 4 + r;
            int a = pa(tok, col);
            float u = fsigmoid(accU[mt][r] + bgu);
            float cnd = ftanh(accC[mt][r] + bcc);
            float sold = toF(Sh[a]) + toF(Sl[a]);
            wplane(Sh, Sl, a, u * sold + (1.0f - u) * cnd);
        }
    __syncthreads();   // state visible; RS reads done
}

__global__ __launch_bounds__(256, 2) void gman_main(
    const float* __restrict__ X, const float* __restrict__ ws,
    const float* __restrict__ Win1, const float* __restrict__ bin1,
    const float* __restrict__ bg1, const float* __restrict__ bc1,
    const float* __restrict__ bg2, const float* __restrict__ bc2,
    const float* __restrict__ bo1, const float* __restrict__ Wo2,
    const float* __restrict__ bo2, float* __restrict__ out) {
    // activation planes: 8 x 8KB = 64 KB
    __shared__ u16 XEh[4096], XEl[4096], S1h[4096], S1l[4096];
    __shared__ u16 S2h[4096], S2l[4096], RSh[4096], RSl[4096];
    __shared__ u32 FRX[4096];                      // +16 KB Win2 frags
    // total 80 KB; 2 blocks/CU

    const int tid = threadIdx.x;
    const int l = tid & 63;
    const int w = tid >> 6;
    const int uw = __builtin_amdgcn_readfirstlane(w);
    const int n16 = l & 15, q = l >> 4;
    const int col = uw * 16 + n16;
    const int b = blockIdx.x >> 4;
    const int nb = blockIdx.x & 15;
    const int n0 = nb << 6;

    const u16* frU = (const u16*)ws;
    const u16* frG1 = frU + uw * 8192;
    const u16* frG2 = frU + 32768 + uw * 8192;
    const u16* frC1 = frU + 65536 + uw * 4096;
    const u16* frC2 = frU + 81920 + uw * 4096;
    const u16* frH  = frU + 106496 + uw * 2048;
    const float* seQ = ws + 57344 + (((nb * 4 + uw) * 64) + l) * 16;
    const float* teo = ws + 122880;

    // stage Win2 frag table (FR_XE, dwords 49152..53247) into LDS
    const u32* frXsrc = (const u32*)ws + 49152;
    #pragma unroll
    for (int i = 0; i < 16; i++) FRX[tid + i * 256] = frXsrc[tid + i * 256];
    const u32* frXL = FRX + uw * 1024;   // per-wave quarter, dword units

    #pragma unroll
    for (int i = 0; i < 16; i++) {
        S1h[tid + i * 256] = 0; S1l[tid + i * 256] = 0;
        S2h[tid + i * 256] = 0; S2l[tid + i * 256] = 0;
    }

    f32x4 se_v[4];
    #pragma unroll
    for (int mt = 0; mt < 4; mt++) se_v[mt] = *(const f32x4*)(seQ + mt * 4);
    const float bg1r = bg1[col], bg1u = bg1[64 + col], bc1c = bc1[col];
    const float bg2r = bg2[col], bg2u = bg2[64 + col], bc2c = bc2[col];

    __syncthreads();   // FRX + S-init visible before first use

    #pragma unroll 1
    for (int p = 0; p < 12; p++) {
        // raw x direct from global (L1-resident row; 4 values per thread)
        const float* xrow = X + (b * 12 + p) * NB + n0;
        float xm[4];
        #pragma unroll
        for (int mt = 0; mt < 4; mt++) xm[mt] = xrow[mt * 16 + n16];
        const float tev = teo[(b * 12 + p) * 64 + col];
        // xe GEMM: A = h1 = relu(x*Win1+bin1) built in regs, B = Win2 quarter (LDS)
        f32x4 accX[4];
        #pragma unroll
        for (int mt = 0; mt < 4; mt++) accX[mt] = (f32x4)0.0f;
        #pragma unroll
        for (int ks = 0; ks < 2; ks++) {
            const int k0 = ks * 32 + q * 8;
            f32x4 w1a = *(const f32x4*)(Win1 + k0), w1b = *(const f32x4*)(Win1 + k0 + 4);
            f32x4 b1a = *(const f32x4*)(bin1 + k0), b1b = *(const f32x4*)(bin1 + k0 + 4);
            bf16x8 bhi = ldfragL(frXL + (ks * 2 + 0) * 256 + l * 4);
            bf16x8 blo = ldfragL(frXL + (ks * 2 + 1) * 256 + l * 4);
            #pragma unroll
            for (int mt = 0; mt < 4; mt++) {
                f32x4 h0, h1v;
                #pragma unroll
                for (int i = 0; i < 4; i++) {
                    h0[i]  = fmaxf(fmaf(xm[mt], w1a[i], b1a[i]), 0.0f);
                    h1v[i] = fmaxf(fmaf(xm[mt], w1b[i], b1b[i]), 0.0f);
                }
                bf16x8 ahi, alo; split8(h0, h1v, ahi, alo);
                accX[mt] = MFMA(ahi, bhi, accX[mt]);
                accX[mt] = MFMA(alo, bhi, accX[mt]);
                accX[mt] = MFMA(ahi, blo, accX[mt]);
            }
        }
        // XE write safe without pre-barrier: last XE reads (gru1 phase 1 of
        // step p-1) retired before p-1's rs barrier.
        #pragma unroll
        for (int mt = 0; mt < 4; mt++)
            #pragma unroll
            for (int r = 0; r < 4; r++) {
                int tok = mt * 16 + q * 4 + r;
                wplane(XEh, XEl, pa(tok, col), accX[mt][r] + se_v[mt][r] + tev);
            }
        __syncthreads();   // XE complete

        gru_full(XEh, XEl, S1h, S1l, RSh, RSl, frG1, frC1, bg1r, bg1u, bc1c, l, col);
        gru_full(S1h, S1l, S2h, S2l, RSh, RSl, frG2, frC2, bg2r, bg2u, bc2c, l, col);
    }

    // head: h = relu(S2@Wo1+bo1) via MFMA into XE planes, then y GEMV
    f32x4 accH[4];
    #pragma unroll
    for (int mt = 0; mt < 4; mt++) accH[mt] = (f32x4)0.0f;
    #pragma unroll
    for (int ks = 0; ks < 2; ks++) {
        bf16x8 bhi = ldfrag(frH + (ks * 2 + 0) * 512 + l * 8);
        bf16x8 blo = ldfrag(frH + (ks * 2 + 1) * 512 + l * 8);
        const int kk = ks * 32 + q * 8;
        #pragma unroll
        for (int mt = 0; mt < 4; mt++) {
            const int fb = pfrag(mt * 16 + n16, kk);
            bf16x8 ahi = ldfrag(S2h + fb);
            bf16x8 alo = ldfrag(S2l + fb);
            accH[mt] = MFMA(ahi, bhi, accH[mt]);
            accH[mt] = MFMA(alo, bhi, accH[mt]);
            accH[mt] = MFMA(ahi, blo, accH[mt]);
        }
    }
    const float bo1c = bo1[col];
    #pragma unroll
    for (int mt = 0; mt < 4; mt++)
        #pragma unroll
        for (int r = 0; r < 4; r++) {
            int tok = mt * 16 + q * 4 + r;
            wplane(XEh, XEl, pa(tok, col), fmaxf(accH[mt][r] + bo1c, 0.0f));
        }
    __syncthreads();
    // y: lane = token. Iteration p8 reads granule position p8^(l&7) -> holds
    // cols p8*8..p8*8+8 for EVERY lane (uniform Wo2 rows, spread banks).
    float y0 = bo2[3 * uw + 0], y1 = bo2[3 * uw + 1], y2 = bo2[3 * uw + 2];
    #pragma unroll
    for (int p8 = 0; p8 < 8; p8++) {
        const int pp = p8 ^ (l & 7);
        i32x4 dh = *(const i32x4*)(XEh + l * 64 + pp * 8);
        i32x4 dl = *(const i32x4*)(XEl + l * 64 + pp * 8);
        #pragma unroll
        for (int e = 0; e < 4; e++) {
            u32 H = (u32)dh[e], L = (u32)dl[e];
            float f0 = __builtin_bit_cast(float, H << 16)
                     + __builtin_bit_cast(float, L << 16);
            float f1 = __builtin_bit_cast(float, H & 0xFFFF0000u)
                     + __builtin_bit_cast(float, L & 0xFFFF0000u);
            int j = p8 * 8 + e * 2;
            y0 = fmaf(f0, Wo2[j * 12 + 3 * uw + 0], y0);
            y1 = fmaf(f0, Wo2[j * 12 + 3 * uw + 1], y1);
            y2 = fmaf(f0, Wo2[j * 12 + 3 * uw + 2], y2);
            y0 = fmaf(f1, Wo2[(j + 1) * 12 + 3 * uw + 0], y0);
            y1 = fmaf(f1, Wo2[(j + 1) * 12 + 3 * uw + 1], y1);
            y2 = fmaf(f1, Wo2[(j + 1) * 12 + 3 * uw + 2], y2);
        }
    }
    out[(b * 12 + 3 * uw + 0) * NB + n0 + l] = y0;
    out[(b * 12 + 3 * uw + 1) * NB + n0 + l] = y1;
    out[(b * 12 + 3 * uw + 2) * NB + n0 + l] = y2;
}

extern "C" void kernel_launch(void* const* d_in, const int* in_sizes, int n_in,
                              void* d_out, int out_size, void* d_ws, size_t ws_size,
                              hipStream_t stream) {
    const float* X    = (const float*)d_in[0];
    // d_in[1]=ZC, d_in[2]=ZF unused by the reference
    const float* SE   = (const float*)d_in[3];
    const float* Wse1 = (const float*)d_in[4];
    const float* bse1 = (const float*)d_in[5];
    const float* Wse2 = (const float*)d_in[6];
    const float* bse2 = (const float*)d_in[7];
    const float* Wte1 = (const float*)d_in[8];
    const float* bte1 = (const float*)d_in[9];
    const float* Wte2 = (const float*)d_in[10];
    const float* bte2 = (const float*)d_in[11];
    const float* Win1 = (const float*)d_in[12];
    const float* bin1 = (const float*)d_in[13];
    const float* Win2 = (const float*)d_in[14];
    const float* bin2 = (const float*)d_in[15];
    const float* Wg1  = (const float*)d_in[16];
    const float* bg1  = (const float*)d_in[17];
    const float* Wc1  = (const float*)d_in[18];
    const float* bc1  = (const float*)d_in[19];
    const float* Wg2  = (const float*)d_in[20];
    const float* bg2  = (const float*)d_in[21];
    const float* Wc2  = (const float*)d_in[22];
    const float* bc2  = (const float*)d_in[23];
    const float* Wo1  = (const float*)d_in[24];
    const float* bo1  = (const float*)d_in[25];
    const float* Wo2  = (const float*)d_in[26];
    const float* bo2  = (const float*)d_in[27];
    const int*   TE   = (const int*)d_in[28];

    float* ws = (float*)d_ws;                  // 172032 floats = 688 KB
    u16* fr = (u16*)ws;
    float* seB = ws + 57344;
    float* teo = ws + 122880;
    float* out = (float*)d_out;

    prep_gates<<<16, 256, 0, stream>>>(Wg1, Wg2, fr);
    prep_cand<<<8, 256, 0, stream>>>(Wc1, Wc2, fr);
    prep_small<<<4, 256, 0, stream>>>(Win2, Wo1, fr);
    prep_se<<<1024, 64, 0, stream>>>(SE, Wse1, bse1, Wse2, bse2, bin2, seB);
    prep_te<<<768, 64, 0, stream>>>(TE, Wte1, bte1, Wte2, bte2, teo);
    gman_main<<<1024, 256, 0, stream>>>(X, ws, Win1, bin1, bg1, bc1, bg2, bc2,
                                        bo1, Wo2, bo2, out);
}

// Round 11
// 753.819 us; speedup vs baseline: 1.0327x; 1.0327x over previous
//
#include <hip/hip_runtime.h>

// GMAN pipeline, fully fused, MFMA edition. support = I -> per-block token GEMMs.
// B=64, P=Q=12, N=1024, D=64. Output [B,Q,N] fp32.
//
// R22 = R21 (split bf16 planes, conflict-free granule swizzle, zero v_perm)
// with the marginal spill fixed.
// R21 post-mortem: VALUBusy 44.9->25.7 (v_perm kill confirmed), bank
// conflicts 37.4M->262K (granule swizzle confirmed), BUT WRITE 126->240MB
// (+114MB = ~4.7 dw/thread/gru marginal spill) and FETCH ->1.34GB. Cause:
// plane A-frags are pure ds_read_b128 with no dependent ALU, so the
// scheduler hoists ALL 4 mt clusters' loads (64 VGPRs in flight) on top of
// 48 B-frag + 48 acc regs -> ~160 live > 128. Fixes:
//  - sched_barrier(0) after each mt cluster in the gru MFMA loops: caps
//    in-flight A-frags at 16 regs (surgical, not global order-pinning).
//  - se_v load moved inside the p-loop (dead during gru phases now).
// Tripwires: WRITE ~126MB flat = spill gone (else revert R20); VGPR<=128.

#define NB 1024

typedef float f32x4 __attribute__((ext_vector_type(4)));
typedef __bf16 bf16x8 __attribute__((ext_vector_type(8)));
typedef int i32x4 __attribute__((ext_vector_type(4)));
typedef unsigned int u32;
typedef unsigned short u16;

#define MFMA(a, b, c) __builtin_amdgcn_mfma_f32_16x16x32_bf16(a, b, c, 0, 0, 0)
#define SCHED_FENCE() __builtin_amdgcn_sched_barrier(0)

__device__ __forceinline__ float fexp(float x) {
    return __builtin_amdgcn_exp2f(x * 1.44269504088896341f);
}
__device__ __forceinline__ float fsigmoid(float x) {
    return __builtin_amdgcn_rcpf(1.0f + fexp(-x));
}
__device__ __forceinline__ float ftanh(float x) {
    return 1.0f - 2.0f * __builtin_amdgcn_rcpf(1.0f + fexp(2.0f * x));
}

__device__ __forceinline__ float toF(u16 h) {
    return __builtin_bit_cast(float, (u32)h << 16);
}
// write v as bf16 hi/lo into the two planes at u16-offset a
__device__ __forceinline__ void wplane(u16* __restrict__ Ph, u16* __restrict__ Pl,
                                       int a, float v) {
    __bf16 h = (__bf16)v;
    Ph[a] = __builtin_bit_cast(u16, h);
    Pl[a] = __builtin_bit_cast(u16, (__bf16)(v - (float)h));
}

__device__ __forceinline__ bf16x8 ldfrag(const u16* p) {
    i32x4 t = *(const i32x4*)p;
    return __builtin_bit_cast(bf16x8, t);
}
// fragment load from an LDS-staged table (ds_read_b128)
__device__ __forceinline__ bf16x8 ldfragL(const u32* p) {
    i32x4 t = *(const i32x4*)p;
    return __builtin_bit_cast(bf16x8, t);
}
__device__ __forceinline__ void split8(f32x4 a0, f32x4 a1, bf16x8& hi, bf16x8& lo) {
    #pragma unroll
    for (int i = 0; i < 4; i++) {
        __bf16 h0 = (__bf16)a0[i]; hi[i] = h0;     lo[i] = (__bf16)(a0[i] - (float)h0);
        __bf16 h1 = (__bf16)a1[i]; hi[4 + i] = h1; lo[4 + i] = (__bf16)(a1[i] - (float)h1);
    }
}

// plane addressing (u16 units). Row = token, 64 cols, 8-col granules (16B).
// Granule position swizzled by row: pos = (col>>3) ^ (row&7).
__device__ __forceinline__ int pa(int tok, int c) {
    return tok * 64 + (((c >> 3) ^ (tok & 7)) << 3) + (c & 7);
}
// frag base: row m, k-window kk (multiple of 8) -> 16B-aligned
__device__ __forceinline__ int pfrag(int m, int kk) {
    return m * 64 + ((((kk) >> 3) ^ (m & 7)) << 3);
}

// ---------------- ws layout (dwords) ----------------
// 0      FR_G1 [wq][nt][ks][half][lane][8bf16] 16384 dw ; 16384 FR_G2
// 32768  FR_C1 [wq][ks][half][lane][8] 8192 dw ; 40960 FR_C2
// 49152  FR_XE Win2 ; 53248 FR_HD Wo1
// 57344  seB [nb(16)][w(4)][lane(64)][16] fp32 (b_in2 folded)  65536 dw
// 122880 teo [768][64] fp32

__device__ __forceinline__ void wsplit(float v, u16* dhi, u16* dlo) {
    __bf16 h = (__bf16)v;
    __bf16 l = (__bf16)(v - (float)h);
    *dhi = __builtin_bit_cast(u16, h);
    *dlo = __builtin_bit_cast(u16, l);
}

__global__ void prep_gates(const float* __restrict__ Wg1, const float* __restrict__ Wg2,
                           u16* __restrict__ fr) {
    int i = blockIdx.x * 256 + threadIdx.x;            // [0, 4096)
    if (i >= 4096) return;
    int layer = i >> 11, r = i & 2047;
    int w = r >> 9; r &= 511; int nt = r >> 8; r &= 255; int ks = r >> 6; int lane = r & 63;
    const float* Wg = layer ? Wg2 : Wg1;
    int n = lane & 15, q = lane >> 4;
    int col = nt ? (64 + w * 16 + n) : (w * 16 + n);
    u16* dst = fr + layer * 32768 + (((w * 2 + nt) * 4 + ks) * 2) * 512 + lane * 8;
    #pragma unroll
    for (int j = 0; j < 8; j++) {
        int k = ks * 32 + q * 8 + j;
        float v = Wg[k * 128 + col] + Wg[(k + 128) * 128 + col];
        wsplit(v, dst + j, dst + 512 + j);
    }
}

__global__ void prep_cand(const float* __restrict__ Wc1, const float* __restrict__ Wc2,
                          u16* __restrict__ fr) {
    int i = blockIdx.x * 256 + threadIdx.x;            // [0, 2048)
    if (i >= 2048) return;
    int layer = i >> 10, r = i & 1023;
    int w = r >> 8; r &= 255; int ks = r >> 6; int lane = r & 63;
    const float* Wc = layer ? Wc2 : Wc1;
    int n = lane & 15, q = lane >> 4;
    int col = w * 16 + n;
    u16* dst = fr + 65536 + layer * 16384 + ((w * 4 + ks) * 2) * 512 + lane * 8;
    #pragma unroll
    for (int j = 0; j < 8; j++) {
        int k = ks * 32 + q * 8 + j;
        float v = Wc[k * 64 + col] + Wc[(k + 128) * 64 + col];
        wsplit(v, dst + j, dst + 512 + j);
    }
}

__global__ void prep_small(const float* __restrict__ Win2, const float* __restrict__ Wo1,
                           u16* __restrict__ fr) {
    int i = blockIdx.x * 256 + threadIdx.x;            // [0, 1024)
    if (i >= 1024) return;
    int kind = i >> 9, r = i & 511;
    int w = r >> 7; r &= 127; int ks = r >> 6; int lane = r & 63;
    const float* W = kind ? Wo1 : Win2;
    int n = lane & 15, q = lane >> 4;
    int col = w * 16 + n;
    u16* dst = fr + 98304 + kind * 8192 + ((w * 2 + ks) * 2) * 512 + lane * 8;
    #pragma unroll
    for (int j = 0; j < 8; j++) {
        int k = ks * 32 + q * 8 + j;
        float v = W[k * 64 + col];
        wsplit(v, dst + j, dst + 512 + j);
    }
}

// se lane-ordered: n = nb*64 + mt*16 + q*4 + r, d = w*16+n16, l = q*16+n16
__global__ void prep_se(const float* __restrict__ SE, const float* __restrict__ W1,
                        const float* __restrict__ b1, const float* __restrict__ W2,
                        const float* __restrict__ b2, const float* __restrict__ bin2,
                        float* __restrict__ seB) {
    __shared__ float h[64];
    int n = blockIdx.x, d = threadIdx.x;
    float acc = b1[d];
    for (int k = 0; k < 64; k++) acc = fmaf(SE[n * 64 + k], W1[k * 64 + d], acc);
    h[d] = fmaxf(acc, 0.0f);
    __syncthreads();
    float acc2 = b2[d];
    for (int k = 0; k < 64; k++) acc2 = fmaf(h[k], W2[k * 64 + d], acc2);
    int nb = n >> 6, tok = n & 63;
    int mt = tok >> 4, q = (tok >> 2) & 3, r = tok & 3;
    int w = d >> 4, n16 = d & 15;
    seB[(((nb * 4 + w) * 64) + q * 16 + n16) * 16 + mt * 4 + r] = acc2 + bin2[d];
}

__global__ void prep_te(const int* __restrict__ TE, const float* __restrict__ W1,
                        const float* __restrict__ b1, const float* __restrict__ W2,
                        const float* __restrict__ b2, float* __restrict__ teo) {
    __shared__ float h[64];
    int bp = blockIdx.x;
    int b = bp / 12, p = bp - b * 12;
    int d = threadIdx.x;
    int dow = TE[(b * 24 + p) * 2 + 0];
    int tod = TE[(b * 24 + p) * 2 + 1];
    float v = W1[dow * 64 + d] + W1[(7 + tod) * 64 + d] + b1[d];
    h[d] = fmaxf(v, 0.0f);
    __syncthreads();
    float acc = b2[d];
    for (int k = 0; k < 64; k++) acc = fmaf(h[k], W2[k * 64 + d], acc);
    teo[bp * 64 + d] = acc;
}

// full GRU step, plane edition. Wave owns cols [16w,16w+16). Gate + cand
// fragments streamed from ws (L2-resident). RS separate planes (alias is
// spill-bait: R19). No soldv (R15 lesson). sched_barrier after each mt
// cluster caps in-flight A-frag regs (R21 spill lesson).
__device__ __forceinline__ void gru_full(
    const u16* __restrict__ XINh, const u16* __restrict__ XINl,
    u16* __restrict__ Sh, u16* __restrict__ Sl,
    u16* __restrict__ RSh, u16* __restrict__ RSl,
    const u16* __restrict__ frG, const u16* __restrict__ frC,
    float bgr, float bgu, float bcc, int l, int col) {
    const int n16 = l & 15, q = l >> 4;
    f32x4 accR[4], accU[4], accC[4];
    #pragma unroll
    for (int mt = 0; mt < 4; mt++) {
        accR[mt] = (f32x4)0.0f; accU[mt] = (f32x4)0.0f; accC[mt] = (f32x4)0.0f;
    }
    // phase 1: ks 0..1 (XIN K-half): one A-frag feeds R+U+C
    #pragma unroll
    for (int ks = 0; ks < 2; ks++) {
        bf16x8 gRh = ldfrag(frG + (ks * 2 + 0) * 512 + l * 8);
        bf16x8 gRl = ldfrag(frG + (ks * 2 + 1) * 512 + l * 8);
        bf16x8 gUh = ldfrag(frG + (8 + ks * 2 + 0) * 512 + l * 8);
        bf16x8 gUl = ldfrag(frG + (8 + ks * 2 + 1) * 512 + l * 8);
        bf16x8 bhiC = ldfrag(frC + (ks * 2 + 0) * 512 + l * 8);
        bf16x8 bloC = ldfrag(frC + (ks * 2 + 1) * 512 + l * 8);
        const int kk = ks * 32 + q * 8;
        #pragma unroll
        for (int mt = 0; mt < 4; mt++) {
            const int fb = pfrag(mt * 16 + n16, kk);
            bf16x8 ahi = ldfrag(XINh + fb);
            bf16x8 alo = ldfrag(XINl + fb);
            accR[mt] = MFMA(ahi, gRh, accR[mt]);
            accR[mt] = MFMA(alo, gRh, accR[mt]);
            accR[mt] = MFMA(ahi, gRl, accR[mt]);
            accU[mt] = MFMA(ahi, gUh, accU[mt]);
            accU[mt] = MFMA(alo, gUh, accU[mt]);
            accU[mt] = MFMA(ahi, gUl, accU[mt]);
            accC[mt] = MFMA(ahi, bhiC, accC[mt]);
            accC[mt] = MFMA(alo, bhiC, accC[mt]);
            accC[mt] = MFMA(ahi, bloC, accC[mt]);
            SCHED_FENCE();   // cap A-frag hoisting: 16 regs in flight max
        }
    }
    // phase 2: ks 2..3 (S K-half): gates only
    #pragma unroll
    for (int ks = 2; ks < 4; ks++) {
        bf16x8 gRh = ldfrag(frG + (ks * 2 + 0) * 512 + l * 8);
        bf16x8 gRl = ldfrag(frG + (ks * 2 + 1) * 512 + l * 8);
        bf16x8 gUh = ldfrag(frG + (8 + ks * 2 + 0) * 512 + l * 8);
        bf16x8 gUl = ldfrag(frG + (8 + ks * 2 + 1) * 512 + l * 8);
        const int kk = (ks - 2) * 32 + q * 8;
        #pragma unroll
        for (int mt = 0; mt < 4; mt++) {
            const int fb = pfrag(mt * 16 + n16, kk);
            bf16x8 ahi = ldfrag(Sh + fb);
            bf16x8 alo = ldfrag(Sl + fb);
            accR[mt] = MFMA(ahi, gRh, accR[mt]);
            accR[mt] = MFMA(alo, gRh, accR[mt]);
            accR[mt] = MFMA(ahi, gRl, accR[mt]);
            accU[mt] = MFMA(ahi, gUh, accU[mt]);
            accU[mt] = MFMA(alo, gUh, accU[mt]);
            accU[mt] = MFMA(ahi, gUl, accU[mt]);
            SCHED_FENCE();
        }
    }
    // rs = sigmoid(r) * s (RS separate planes -> no barrier needed first)
    #pragma unroll
    for (int mt = 0; mt < 4; mt++)
        #pragma unroll
        for (int r = 0; r < 4; r++) {
            int tok = mt * 16 + q * 4 + r;
            int a = pa(tok, col);
            float sold = toF(Sh[a]) + toF(Sl[a]);
            wplane(RSh, RSl, a, fsigmoid(accR[mt][r] + bgr) * sold);
        }
    __syncthreads();   // rs visible
    // cand ks 2..3 (RS K-half)
    #pragma unroll
    for (int ks = 2; ks < 4; ks++) {
        bf16x8 bhi = ldfrag(frC + (ks * 2 + 0) * 512 + l * 8);
        bf16x8 blo = ldfrag(frC + (ks * 2 + 1) * 512 + l * 8);
        const int kk = (ks - 2) * 32 + q * 8;
        #pragma unroll
        for (int mt = 0; mt < 4; mt++) {
            const int fb = pfrag(mt * 16 + n16, kk);
            bf16x8 ahi = ldfrag(RSh + fb);
            bf16x8 alo = ldfrag(RSl + fb);
            accC[mt] = MFMA(ahi, bhi, accC[mt]);
            accC[mt] = MFMA(alo, bhi, accC[mt]);
            accC[mt] = MFMA(ahi, blo, accC[mt]);
            SCHED_FENCE();
        }
    }
    // state update (sold re-read from planes: same thread, same address)
    #pragma unroll
    for (int mt = 0; mt < 4; mt++)
        #pragma unroll
        for (int r = 0; r < 4; r++) {
            int tok = mt * 16 + q * 4 + r;
            int a = pa(tok, col);
            float u = fsigmoid(accU[mt][r] + bgu);
            float cnd = ftanh(accC[mt][r] + bcc);
            float sold = toF(Sh[a]) + toF(Sl[a]);
            wplane(Sh, Sl, a, u * sold + (1.0f - u) * cnd);
        }
    __syncthreads();   // state visible; RS reads done
}

__global__ __launch_bounds__(256, 2) void gman_main(
    const float* __restrict__ X, const float* __restrict__ ws,
    const float* __restrict__ Win1, const float* __restrict__ bin1,
    const float* __restrict__ bg1, const float* __restrict__ bc1,
    const float* __restrict__ bg2, const float* __restrict__ bc2,
    const float* __restrict__ bo1, const float* __restrict__ Wo2,
    const float* __restrict__ bo2, float* __restrict__ out) {
    // activation planes: 8 x 8KB = 64 KB
    __shared__ u16 XEh[4096], XEl[4096], S1h[4096], S1l[4096];
    __shared__ u16 S2h[4096], S2l[4096], RSh[4096], RSl[4096];
    __shared__ u32 FRX[4096];                      // +16 KB Win2 frags
    // total 80 KB; 2 blocks/CU

    const int tid = threadIdx.x;
    const int l = tid & 63;
    const int w = tid >> 6;
    const int uw = __builtin_amdgcn_readfirstlane(w);
    const int n16 = l & 15, q = l >> 4;
    const int col = uw * 16 + n16;
    const int b = blockIdx.x >> 4;
    const int nb = blockIdx.x & 15;
    const int n0 = nb << 6;

    const u16* frU = (const u16*)ws;
    const u16* frG1 = frU + uw * 8192;
    const u16* frG2 = frU + 32768 + uw * 8192;
    const u16* frC1 = frU + 65536 + uw * 4096;
    const u16* frC2 = frU + 81920 + uw * 4096;
    const u16* frH  = frU + 106496 + uw * 2048;
    const float* seQ = ws + 57344 + (((nb * 4 + uw) * 64) + l) * 16;
    const float* teo = ws + 122880;

    // stage Win2 frag table (FR_XE, dwords 49152..53247) into LDS
    const u32* frXsrc = (const u32*)ws + 49152;
    #pragma unroll
    for (int i = 0; i < 16; i++) FRX[tid + i * 256] = frXsrc[tid + i * 256];
    const u32* frXL = FRX + uw * 1024;   // per-wave quarter, dword units

    #pragma unroll
    for (int i = 0; i < 16; i++) {
        S1h[tid + i * 256] = 0; S1l[tid + i * 256] = 0;
        S2h[tid + i * 256] = 0; S2l[tid + i * 256] = 0;
    }

    const float bg1r = bg1[col], bg1u = bg1[64 + col], bc1c = bc1[col];
    const float bg2r = bg2[col], bg2u = bg2[64 + col], bc2c = bc2[col];

    __syncthreads();   // FRX + S-init visible before first use

    #pragma unroll 1
    for (int p = 0; p < 12; p++) {
        // raw x direct from global (L1-resident row; 4 values per thread);
        // se_v loaded per-step (dead during gru phases -> lower pressure)
        const float* xrow = X + (b * 12 + p) * NB + n0;
        float xm[4];
        #pragma unroll
        for (int mt = 0; mt < 4; mt++) xm[mt] = xrow[mt * 16 + n16];
        f32x4 se_v[4];
        #pragma unroll
        for (int mt = 0; mt < 4; mt++) se_v[mt] = *(const f32x4*)(seQ + mt * 4);
        const float tev = teo[(b * 12 + p) * 64 + col];
        // xe GEMM: A = h1 = relu(x*Win1+bin1) built in regs, B = Win2 quarter (LDS)
        f32x4 accX[4];
        #pragma unroll
        for (int mt = 0; mt < 4; mt++) accX[mt] = (f32x4)0.0f;
        #pragma unroll
        for (int ks = 0; ks < 2; ks++) {
            const int k0 = ks * 32 + q * 8;
            f32x4 w1a = *(const f32x4*)(Win1 + k0), w1b = *(const f32x4*)(Win1 + k0 + 4);
            f32x4 b1a = *(const f32x4*)(bin1 + k0), b1b = *(const f32x4*)(bin1 + k0 + 4);
            bf16x8 bhi = ldfragL(frXL + (ks * 2 + 0) * 256 + l * 4);
            bf16x8 blo = ldfragL(frXL + (ks * 2 + 1) * 256 + l * 4);
            #pragma unroll
            for (int mt = 0; mt < 4; mt++) {
                f32x4 h0, h1v;
                #pragma unroll
                for (int i = 0; i < 4; i++) {
                    h0[i]  = fmaxf(fmaf(xm[mt], w1a[i], b1a[i]), 0.0f);
                    h1v[i] = fmaxf(fmaf(xm[mt], w1b[i], b1b[i]), 0.0f);
                }
                bf16x8 ahi, alo; split8(h0, h1v, ahi, alo);
                accX[mt] = MFMA(ahi, bhi, accX[mt]);
                accX[mt] = MFMA(alo, bhi, accX[mt]);
                accX[mt] = MFMA(ahi, blo, accX[mt]);
            }
        }
        // XE write safe without pre-barrier: last XE reads (gru1 phase 1 of
        // step p-1) retired before p-1's rs barrier.
        #pragma unroll
        for (int mt = 0; mt < 4; mt++)
            #pragma unroll
            for (int r = 0; r < 4; r++) {
                int tok = mt * 16 + q * 4 + r;
                wplane(XEh, XEl, pa(tok, col), accX[mt][r] + se_v[mt][r] + tev);
            }
        __syncthreads();   // XE complete

        gru_full(XEh, XEl, S1h, S1l, RSh, RSl, frG1, frC1, bg1r, bg1u, bc1c, l, col);
        gru_full(S1h, S1l, S2h, S2l, RSh, RSl, frG2, frC2, bg2r, bg2u, bc2c, l, col);
    }

    // head: h = relu(S2@Wo1+bo1) via MFMA into XE planes, then y GEMV
    f32x4 accH[4];
    #pragma unroll
    for (int mt = 0; mt < 4; mt++) accH[mt] = (f32x4)0.0f;
    #pragma unroll
    for (int ks = 0; ks < 2; ks++) {
        bf16x8 bhi = ldfrag(frH + (ks * 2 + 0) * 512 + l * 8);
        bf16x8 blo = ldfrag(frH + (ks * 2 + 1) * 512 + l * 8);
        const int kk = ks * 32 + q * 8;
        #pragma unroll
        for (int mt = 0; mt < 4; mt++) {
            const int fb = pfrag(mt * 16 + n16, kk);
            bf16x8 ahi = ldfrag(S2h + fb);
            bf16x8 alo = ldfrag(S2l + fb);
            accH[mt] = MFMA(ahi, bhi, accH[mt]);
            accH[mt] = MFMA(alo, bhi, accH[mt]);
            accH[mt] = MFMA(ahi, blo, accH[mt]);
        }
    }
    const float bo1c = bo1[col];
    #pragma unroll
    for (int mt = 0; mt < 4; mt++)
        #pragma unroll
        for (int r = 0; r < 4; r++) {
            int tok = mt * 16 + q * 4 + r;
            wplane(XEh, XEl, pa(tok, col), fmaxf(accH[mt][r] + bo1c, 0.0f));
        }
    __syncthreads();
    // y: lane = token. Iteration p8 reads granule position p8^(l&7) -> holds
    // cols p8*8..p8*8+8 for EVERY lane (uniform Wo2 rows, spread banks).
    float y0 = bo2[3 * uw + 0], y1 = bo2[3 * uw + 1], y2 = bo2[3 * uw + 2];
    #pragma unroll
    for (int p8 = 0; p8 < 8; p8++) {
        const int pp = p8 ^ (l & 7);
        i32x4 dh = *(const i32x4*)(XEh + l * 64 + pp * 8);
        i32x4 dl = *(const i32x4*)(XEl + l * 64 + pp * 8);
        #pragma unroll
        for (int e = 0; e < 4; e++) {
            u32 H = (u32)dh[e], L = (u32)dl[e];
            float f0 = __builtin_bit_cast(float, H << 16)
                     + __builtin_bit_cast(float, L << 16);
            float f1 = __builtin_bit_cast(float, H & 0xFFFF0000u)
                     + __builtin_bit_cast(float, L & 0xFFFF0000u);
            int j = p8 * 8 + e * 2;
            y0 = fmaf(f0, Wo2[j * 12 + 3 * uw + 0], y0);
            y1 = fmaf(f0, Wo2[j * 12 + 3 * uw + 1], y1);
            y2 = fmaf(f0, Wo2[j * 12 + 3 * uw + 2], y2);
            y0 = fmaf(f1, Wo2[(j + 1) * 12 + 3 * uw + 0], y0);
            y1 = fmaf(f1, Wo2[(j + 1) * 12 + 3 * uw + 1], y1);
            y2 = fmaf(f1, Wo2[(j + 1) * 12 + 3 * uw + 2], y2);
        }
    }
    out[(b * 12 + 3 * uw + 0) * NB + n0 + l] = y0;
    out[(b * 12 + 3 * uw + 1) * NB + n0 + l] = y1;
    out[(b * 12 + 3 * uw + 2) * NB + n0 + l] = y2;
}

extern "C" void kernel_launch(void* const* d_in, const int* in_sizes, int n_in,
                              void* d_out, int out_size, void* d_ws, size_t ws_size,
                              hipStream_t stream) {
    const float* X    = (const float*)d_in[0];
    // d_in[1]=ZC, d_in[2]=ZF unused by the reference
    const float* SE   = (const float*)d_in[3];
    const float* Wse1 = (const float*)d_in[4];
    const float* bse1 = (const float*)d_in[5];
    const float* Wse2 = (const float*)d_in[6];
    const float* bse2 = (const float*)d_in[7];
    const float* Wte1 = (const float*)d_in[8];
    const float* bte1 = (const float*)d_in[9];
    const float* Wte2 = (const float*)d_in[10];
    const float* bte2 = (const float*)d_in[11];
    const float* Win1 = (const float*)d_in[12];
    const float* bin1 = (const float*)d_in[13];
    const float* Win2 = (const float*)d_in[14];
    const float* bin2 = (const float*)d_in[15];
    const float* Wg1  = (const float*)d_in[16];
    const float* bg1  = (const float*)d_in[17];
    const float* Wc1  = (const float*)d_in[18];
    const float* bc1  = (const float*)d_in[19];
    const float* Wg2  = (const float*)d_in[20];
    const float* bg2  = (const float*)d_in[21];
    const float* Wc2  = (const float*)d_in[22];
    const float* bc2  = (const float*)d_in[23];
    const float* Wo1  = (const float*)d_in[24];
    const float* bo1  = (const float*)d_in[25];
    const float* Wo2  = (const float*)d_in[26];
    const float* bo2  = (const float*)d_in[27];
    const int*   TE   = (const int*)d_in[28];

    float* ws = (float*)d_ws;                  // 172032 floats = 688 KB
    u16* fr = (u16*)ws;
    float* seB = ws + 57344;
    float* teo = ws + 122880;
    float* out = (float*)d_out;

    prep_gates<<<16, 256, 0, stream>>>(Wg1, Wg2, fr);
    prep_cand<<<8, 256, 0, stream>>>(Wc1, Wc2, fr);
    prep_small<<<4, 256, 0, stream>>>(Win2, Wo1, fr);
    prep_se<<<1024, 64, 0, stream>>>(SE, Wse1, bse1, Wse2, bse2, bin2, seB);
    prep_te<<<768, 64, 0, stream>>>(TE, Wte1, bte1, Wte2, bte2, teo);
    gman_main<<<1024, 256, 0, stream>>>(X, ws, Win1, bin1, bg1, bc1, bg2, bc2,
                                        bo1, Wo2, bo2, out);
}

// Round 12
// 629.872 us; speedup vs baseline: 1.2360x; 1.1968x over previous
//
#include <hip/hip_runtime.h>

// GMAN pipeline, fully fused, MFMA edition. support = I -> per-block token GEMMs.
// B=64, P=Q=12, N=1024, D=64. Output [B,Q,N] fp32.
//
// R23 = R20 (467us: packed dwords, FRX staged, direct-x, no spill) + xe-GEMM
// folded into gru2's barrier shadow.
// Evidence trail:
//  - R21/R22: split-plane format = structural ~128MB spill (sched fences had
//    ZERO effect; scalar phases need 2x u16 LDS ops + addresses). CLOSED.
//    Packed-dword + v_perm (only ~35us of the 210us VALU time) is correct
//    at the 128-reg budget.
//  - R20 law: barrier/instruction cuts pay; byte cuts don't (~32% no-issue
//    stall at fixed 8 waves/CU).
//  - R23: XE is last read in gru1-ph1 (3 barriers before gru2's cand), so
//    xe(p+1) (depends only on global X) computes inside gru2's rs->update
//    region, writing XE there. gru2's update barrier publishes XE + S2
//    together: 5 -> 4 barriers/p-step, and xe's 24 MFMA + ~400 VALU overlap
//    cand-phase. Pressure in that region: accU+accC(32, accR dead) +
//    accX(16) + temps ~ 96 < 128.
// Tripwires: WRITE >160MB = xe-fold over-pressures -> revert to R20.

#define NB 1024

typedef float f32x4 __attribute__((ext_vector_type(4)));
typedef __bf16 bf16x8 __attribute__((ext_vector_type(8)));
typedef int i32x4 __attribute__((ext_vector_type(4)));
typedef unsigned int u32;
typedef unsigned short u16;

#define MFMA(a, b, c) __builtin_amdgcn_mfma_f32_16x16x32_bf16(a, b, c, 0, 0, 0)

__device__ __forceinline__ float fexp(float x) {
    return __builtin_amdgcn_exp2f(x * 1.44269504088896341f);
}
__device__ __forceinline__ float fsigmoid(float x) {
    return __builtin_amdgcn_rcpf(1.0f + fexp(-x));
}
__device__ __forceinline__ float ftanh(float x) {
    return 1.0f - 2.0f * __builtin_amdgcn_rcpf(1.0f + fexp(2.0f * x));
}

// pack fp32 -> {bf16 hi | bf16 lo} in one dword (truncation split)
__device__ __forceinline__ u32 packf(float v) {
    u32 u = __builtin_bit_cast(u32, v);
    u32 hb = u & 0xFFFF0000u;
    float lo = v - __builtin_bit_cast(float, hb);
    return hb | (__builtin_bit_cast(u32, lo) >> 16);
}
__device__ __forceinline__ float unpackf(u32 u) {
    return __builtin_bit_cast(float, u & 0xFFFF0000u)
         + __builtin_bit_cast(float, u << 16);
}

__device__ __forceinline__ bf16x8 ldfrag(const u16* p) {
    i32x4 t = *(const i32x4*)p;
    return __builtin_bit_cast(bf16x8, t);
}
// fragment load from an LDS-staged table (ds_read_b128)
__device__ __forceinline__ bf16x8 ldfragL(const u32* p) {
    i32x4 t = *(const i32x4*)p;
    return __builtin_bit_cast(bf16x8, t);
}
__device__ __forceinline__ void split8(f32x4 a0, f32x4 a1, bf16x8& hi, bf16x8& lo) {
    #pragma unroll
    for (int i = 0; i < 4; i++) {
        __bf16 h0 = (__bf16)a0[i]; hi[i] = h0;     lo[i] = (__bf16)(a0[i] - (float)h0);
        __bf16 h1 = (__bf16)a1[i]; hi[4 + i] = h1; lo[4 + i] = (__bf16)(a1[i] - (float)h1);
    }
}

// swizzle: xor k bits 2..4 by t bits; k bits 0-1 intact -> 4-dword windows legal
#define SWZ(t) ((((t) & 3) << 3) ^ ((t) & 4) ^ (((t) & 8) << 1))
#define SW(t, k) ((t) * 64 + ((k) ^ SWZ(t)))

// read packed A-frag: 8 consecutive k from swizzled row m, extract hi/lo via v_perm
__device__ __forceinline__ void lda_packed(const u32* __restrict__ src, int m, int kk,
                                           bf16x8& hi, bf16x8& lo) {
    const int sk = kk ^ SWZ(m);
    i32x4 d0 = *(const i32x4*)(src + m * 64 + sk);
    i32x4 d1 = *(const i32x4*)(src + m * 64 + (sk ^ 4));
    i32x4 h, L;
    h[0] = (int)__builtin_amdgcn_perm((u32)d0[1], (u32)d0[0], 0x07060302u);
    h[1] = (int)__builtin_amdgcn_perm((u32)d0[3], (u32)d0[2], 0x07060302u);
    h[2] = (int)__builtin_amdgcn_perm((u32)d1[1], (u32)d1[0], 0x07060302u);
    h[3] = (int)__builtin_amdgcn_perm((u32)d1[3], (u32)d1[2], 0x07060302u);
    L[0] = (int)__builtin_amdgcn_perm((u32)d0[1], (u32)d0[0], 0x05040100u);
    L[1] = (int)__builtin_amdgcn_perm((u32)d0[3], (u32)d0[2], 0x05040100u);
    L[2] = (int)__builtin_amdgcn_perm((u32)d1[1], (u32)d1[0], 0x05040100u);
    L[3] = (int)__builtin_amdgcn_perm((u32)d1[3], (u32)d1[2], 0x05040100u);
    hi = __builtin_bit_cast(bf16x8, h);
    lo = __builtin_bit_cast(bf16x8, L);
}

// ---------------- ws layout (dwords) ----------------
// 0      FR_G1 [wq][nt][ks][half][lane][8bf16] 16384 dw ; 16384 FR_G2
// 32768  FR_C1 [wq][ks][half][lane][8] 8192 dw ; 40960 FR_C2
// 49152  FR_XE Win2 ; 53248 FR_HD Wo1
// 57344  seB [nb(16)][w(4)][lane(64)][16] fp32 (b_in2 folded)  65536 dw
// 122880 teo [768][64] fp32

__device__ __forceinline__ void wsplit(float v, u16* dhi, u16* dlo) {
    __bf16 h = (__bf16)v;
    __bf16 l = (__bf16)(v - (float)h);
    *dhi = __builtin_bit_cast(u16, h);
    *dlo = __builtin_bit_cast(u16, l);
}

__global__ void prep_gates(const float* __restrict__ Wg1, const float* __restrict__ Wg2,
                           u16* __restrict__ fr) {
    int i = blockIdx.x * 256 + threadIdx.x;            // [0, 4096)
    if (i >= 4096) return;
    int layer = i >> 11, r = i & 2047;
    int w = r >> 9; r &= 511; int nt = r >> 8; r &= 255; int ks = r >> 6; int lane = r & 63;
    const float* Wg = layer ? Wg2 : Wg1;
    int n = lane & 15, q = lane >> 4;
    int col = nt ? (64 + w * 16 + n) : (w * 16 + n);
    u16* dst = fr + layer * 32768 + (((w * 2 + nt) * 4 + ks) * 2) * 512 + lane * 8;
    #pragma unroll
    for (int j = 0; j < 8; j++) {
        int k = ks * 32 + q * 8 + j;
        float v = Wg[k * 128 + col] + Wg[(k + 128) * 128 + col];
        wsplit(v, dst + j, dst + 512 + j);
    }
}

__global__ void prep_cand(const float* __restrict__ Wc1, const float* __restrict__ Wc2,
                          u16* __restrict__ fr) {
    int i = blockIdx.x * 256 + threadIdx.x;            // [0, 2048)
    if (i >= 2048) return;
    int layer = i >> 10, r = i & 1023;
    int w = r >> 8; r &= 255; int ks = r >> 6; int lane = r & 63;
    const float* Wc = layer ? Wc2 : Wc1;
    int n = lane & 15, q = lane >> 4;
    int col = w * 16 + n;
    u16* dst = fr + 65536 + layer * 16384 + ((w * 4 + ks) * 2) * 512 + lane * 8;
    #pragma unroll
    for (int j = 0; j < 8; j++) {
        int k = ks * 32 + q * 8 + j;
        float v = Wc[k * 64 + col] + Wc[(k + 128) * 64 + col];
        wsplit(v, dst + j, dst + 512 + j);
    }
}

__global__ void prep_small(const float* __restrict__ Win2, const float* __restrict__ Wo1,
                           u16* __restrict__ fr) {
    int i = blockIdx.x * 256 + threadIdx.x;            // [0, 1024)
    if (i >= 1024) return;
    int kind = i >> 9, r = i & 511;
    int w = r >> 7; r &= 127; int ks = r >> 6; int lane = r & 63;
    const float* W = kind ? Wo1 : Win2;
    int n = lane & 15, q = lane >> 4;
    int col = w * 16 + n;
    u16* dst = fr + 98304 + kind * 8192 + ((w * 2 + ks) * 2) * 512 + lane * 8;
    #pragma unroll
    for (int j = 0; j < 8; j++) {
        int k = ks * 32 + q * 8 + j;
        float v = W[k * 64 + col];
        wsplit(v, dst + j, dst + 512 + j);
    }
}

// se lane-ordered: n = nb*64 + mt*16 + q*4 + r, d = w*16+n16, l = q*16+n16
__global__ void prep_se(const float* __restrict__ SE, const float* __restrict__ W1,
                        const float* __restrict__ b1, const float* __restrict__ W2,
                        const float* __restrict__ b2, const float* __restrict__ bin2,
                        float* __restrict__ seB) {
    __shared__ float h[64];
    int n = blockIdx.x, d = threadIdx.x;
    float acc = b1[d];
    for (int k = 0; k < 64; k++) acc = fmaf(SE[n * 64 + k], W1[k * 64 + d], acc);
    h[d] = fmaxf(acc, 0.0f);
    __syncthreads();
    float acc2 = b2[d];
    for (int k = 0; k < 64; k++) acc2 = fmaf(h[k], W2[k * 64 + d], acc2);
    int nb = n >> 6, tok = n & 63;
    int mt = tok >> 4, q = (tok >> 2) & 3, r = tok & 3;
    int w = d >> 4, n16 = d & 15;
    seB[(((nb * 4 + w) * 64) + q * 16 + n16) * 16 + mt * 4 + r] = acc2 + bin2[d];
}

__global__ void prep_te(const int* __restrict__ TE, const float* __restrict__ W1,
                        const float* __restrict__ b1, const float* __restrict__ W2,
                        const float* __restrict__ b2, float* __restrict__ teo) {
    __shared__ float h[64];
    int bp = blockIdx.x;
    int b = bp / 12, p = bp - b * 12;
    int d = threadIdx.x;
    int dow = TE[(b * 24 + p) * 2 + 0];
    int tod = TE[(b * 24 + p) * 2 + 1];
    float v = W1[dow * 64 + d] + W1[(7 + tod) * 64 + d] + b1[d];
    h[d] = fmaxf(v, 0.0f);
    __syncthreads();
    float acc = b2[d];
    for (int k = 0; k < 64; k++) acc = fmaf(h[k], W2[k * 64 + d], acc);
    teo[bp * 64 + d] = acc;
}

// xe-GEMM for step bp: A = h1 = relu(x*Win1+bin1) built in regs,
// B = Win2 quarter (LDS-staged). Writes packed XE.
__device__ __forceinline__ void do_xe(
    const float* __restrict__ X, const float* __restrict__ Win1,
    const float* __restrict__ bin1, const u32* __restrict__ frXL,
    const float* __restrict__ teo, u32* __restrict__ XE,
    const f32x4 (&se_v)[4], int bp, int n0, int l, int col) {
    const int n16 = l & 15, q = l >> 4;
    const float* xrow = X + bp * NB + n0;
    float xm[4];
    #pragma unroll
    for (int mt = 0; mt < 4; mt++) xm[mt] = xrow[mt * 16 + n16];
    const float tev = teo[bp * 64 + col];
    f32x4 accX[4];
    #pragma unroll
    for (int mt = 0; mt < 4; mt++) accX[mt] = (f32x4)0.0f;
    #pragma unroll
    for (int ks = 0; ks < 2; ks++) {
        const int k0 = ks * 32 + q * 8;
        f32x4 w1a = *(const f32x4*)(Win1 + k0), w1b = *(const f32x4*)(Win1 + k0 + 4);
        f32x4 b1a = *(const f32x4*)(bin1 + k0), b1b = *(const f32x4*)(bin1 + k0 + 4);
        bf16x8 bhi = ldfragL(frXL + (ks * 2 + 0) * 256 + l * 4);
        bf16x8 blo = ldfragL(frXL + (ks * 2 + 1) * 256 + l * 4);
        #pragma unroll
        for (int mt = 0; mt < 4; mt++) {
            f32x4 h0, h1v;
            #pragma unroll
            for (int i = 0; i < 4; i++) {
                h0[i]  = fmaxf(fmaf(xm[mt], w1a[i], b1a[i]), 0.0f);
                h1v[i] = fmaxf(fmaf(xm[mt], w1b[i], b1b[i]), 0.0f);
            }
            bf16x8 ahi, alo; split8(h0, h1v, ahi, alo);
            accX[mt] = MFMA(ahi, bhi, accX[mt]);
            accX[mt] = MFMA(alo, bhi, accX[mt]);
            accX[mt] = MFMA(ahi, blo, accX[mt]);
        }
    }
    #pragma unroll
    for (int mt = 0; mt < 4; mt++)
        #pragma unroll
        for (int r = 0; r < 4; r++) {
            int tok = mt * 16 + q * 4 + r;
            XE[SW(tok, col)] = packf(accX[mt][r] + se_v[mt][r] + tev);
        }
}

// full GRU step. Wave owns cols [16w,16w+16). Gate + cand fragments streamed
// from ws (L2-resident; remat beats spill at the 128-reg budget). RS is a
// SEPARATE buffer (alias is spill-bait: R19). No soldv (R15 lesson).
// mid() runs in the rs-barrier -> update-barrier shadow (xe-fold for gru2).
template <typename MidF>
__device__ __forceinline__ void gru_full(
    const u32* __restrict__ XIN, u32* __restrict__ S, u32* __restrict__ RS,
    const u16* __restrict__ frG, const u16* __restrict__ frC,
    float bgr, float bgu, float bcc, int l, int col, MidF&& mid) {
    const int n16 = l & 15, q = l >> 4;
    f32x4 accR[4], accU[4], accC[4];
    #pragma unroll
    for (int mt = 0; mt < 4; mt++) {
        accR[mt] = (f32x4)0.0f; accU[mt] = (f32x4)0.0f; accC[mt] = (f32x4)0.0f;
    }
    // phase 1: ks 0..1 (XIN K-half): one A-frag feeds R+U+C
    #pragma unroll
    for (int ks = 0; ks < 2; ks++) {
        bf16x8 gRh = ldfrag(frG + (ks * 2 + 0) * 512 + l * 8);
        bf16x8 gRl = ldfrag(frG + (ks * 2 + 1) * 512 + l * 8);
        bf16x8 gUh = ldfrag(frG + (8 + ks * 2 + 0) * 512 + l * 8);
        bf16x8 gUl = ldfrag(frG + (8 + ks * 2 + 1) * 512 + l * 8);
        bf16x8 bhiC = ldfrag(frC + (ks * 2 + 0) * 512 + l * 8);
        bf16x8 bloC = ldfrag(frC + (ks * 2 + 1) * 512 + l * 8);
        const int kk = ks * 32 + q * 8;
        #pragma unroll
        for (int mt = 0; mt < 4; mt++) {
            bf16x8 ahi, alo;
            lda_packed(XIN, mt * 16 + n16, kk, ahi, alo);
            accR[mt] = MFMA(ahi, gRh, accR[mt]);
            accR[mt] = MFMA(alo, gRh, accR[mt]);
            accR[mt] = MFMA(ahi, gRl, accR[mt]);
            accU[mt] = MFMA(ahi, gUh, accU[mt]);
            accU[mt] = MFMA(alo, gUh, accU[mt]);
            accU[mt] = MFMA(ahi, gUl, accU[mt]);
            accC[mt] = MFMA(ahi, bhiC, accC[mt]);
            accC[mt] = MFMA(alo, bhiC, accC[mt]);
            accC[mt] = MFMA(ahi, bloC, accC[mt]);
        }
    }
    // phase 2: ks 2..3 (S K-half): gates only
    #pragma unroll
    for (int ks = 2; ks < 4; ks++) {
        bf16x8 gRh = ldfrag(frG + (ks * 2 + 0) * 512 + l * 8);
        bf16x8 gRl = ldfrag(frG + (ks * 2 + 1) * 512 + l * 8);
        bf16x8 gUh = ldfrag(frG + (8 + ks * 2 + 0) * 512 + l * 8);
        bf16x8 gUl = ldfrag(frG + (8 + ks * 2 + 1) * 512 + l * 8);
        const int kk = (ks - 2) * 32 + q * 8;
        #pragma unroll
        for (int mt = 0; mt < 4; mt++) {
            bf16x8 ahi, alo;
            lda_packed(S, mt * 16 + n16, kk, ahi, alo);
            accR[mt] = MFMA(ahi, gRh, accR[mt]);
            accR[mt] = MFMA(alo, gRh, accR[mt]);
            accR[mt] = MFMA(ahi, gRl, accR[mt]);
            accU[mt] = MFMA(ahi, gUh, accU[mt]);
            accU[mt] = MFMA(alo, gUh, accU[mt]);
            accU[mt] = MFMA(ahi, gUl, accU[mt]);
        }
    }
    // rs = sigmoid(r) * s (RS separate buffer -> no barrier needed first)
    #pragma unroll
    for (int mt = 0; mt < 4; mt++)
        #pragma unroll
        for (int r = 0; r < 4; r++) {
            int tok = mt * 16 + q * 4 + r;
            int a = SW(tok, col);
            RS[a] = packf(fsigmoid(accR[mt][r] + bgr) * unpackf(S[a]));
        }
    __syncthreads();   // rs visible
    mid();             // xe(p+1) fold (gru2 only): XE dead since gru1-ph1
    // cand ks 2..3 (RS K-half)
    #pragma unroll
    for (int ks = 2; ks < 4; ks++) {
        bf16x8 bhi = ldfrag(frC + (ks * 2 + 0) * 512 + l * 8);
        bf16x8 blo = ldfrag(frC + (ks * 2 + 1) * 512 + l * 8);
        const int kk = (ks - 2) * 32 + q * 8;
        #pragma unroll
        for (int mt = 0; mt < 4; mt++) {
            bf16x8 ahi, alo;
            lda_packed(RS, mt * 16 + n16, kk, ahi, alo);
            accC[mt] = MFMA(ahi, bhi, accC[mt]);
            accC[mt] = MFMA(alo, bhi, accC[mt]);
            accC[mt] = MFMA(ahi, blo, accC[mt]);
        }
    }
    // state update (sold re-read from LDS: same thread, same address)
    #pragma unroll
    for (int mt = 0; mt < 4; mt++)
        #pragma unroll
        for (int r = 0; r < 4; r++) {
            int tok = mt * 16 + q * 4 + r;
            int a = SW(tok, col);
            float u = fsigmoid(accU[mt][r] + bgu);
            float cnd = ftanh(accC[mt][r] + bcc);
            float sold = unpackf(S[a]);
            S[a] = packf(u * sold + (1.0f - u) * cnd);
        }
    __syncthreads();   // state + (folded XE) visible; RS reads done
}

__global__ __launch_bounds__(256, 2) void gman_main(
    const float* __restrict__ X, const float* __restrict__ ws,
    const float* __restrict__ Win1, const float* __restrict__ bin1,
    const float* __restrict__ bg1, const float* __restrict__ bc1,
    const float* __restrict__ bg2, const float* __restrict__ bc2,
    const float* __restrict__ bo1, const float* __restrict__ Wo2,
    const float* __restrict__ bo2, float* __restrict__ out) {
    __shared__ u32 XE[4096], S1[4096], S2[4096], RS[4096];   // 64 KB
    __shared__ u32 FRX[4096];                                // +16 KB Win2 frags
    // total 80 KB; 2 blocks/CU

    const int tid = threadIdx.x;
    const int l = tid & 63;
    const int w = tid >> 6;
    const int uw = __builtin_amdgcn_readfirstlane(w);
    const int n16 = l & 15, q = l >> 4;
    const int col = uw * 16 + n16;
    const int b = blockIdx.x >> 4;
    const int nb = blockIdx.x & 15;
    const int n0 = nb << 6;

    const u16* frU = (const u16*)ws;
    const u16* frG1 = frU + uw * 8192;
    const u16* frG2 = frU + 32768 + uw * 8192;
    const u16* frC1 = frU + 65536 + uw * 4096;
    const u16* frC2 = frU + 81920 + uw * 4096;
    const u16* frH  = frU + 106496 + uw * 2048;
    const float* seQ = ws + 57344 + (((nb * 4 + uw) * 64) + l) * 16;
    const float* teo = ws + 122880;

    // stage Win2 frag table (FR_XE, dwords 49152..53247) into LDS
    const u32* frXsrc = (const u32*)ws + 49152;
    #pragma unroll
    for (int i = 0; i < 16; i++) FRX[tid + i * 256] = frXsrc[tid + i * 256];
    const u32* frXL = FRX + uw * 1024;   // per-wave quarter, dword units

    #pragma unroll
    for (int i = 0; i < 16; i++) { S1[tid + i * 256] = 0u; S2[tid + i * 256] = 0u; }

    f32x4 se_v[4];
    #pragma unroll
    for (int mt = 0; mt < 4; mt++) se_v[mt] = *(const f32x4*)(seQ + mt * 4);
    const float bg1r = bg1[col], bg1u = bg1[64 + col], bc1c = bc1[col];
    const float bg2r = bg2[col], bg2u = bg2[64 + col], bc2c = bc2[col];

    __syncthreads();   // FRX + S-init visible

    // prologue: xe(0)
    do_xe(X, Win1, bin1, frXL, teo, XE, se_v, b * 12 + 0, n0, l, col);
    __syncthreads();   // XE(0) complete

    #pragma unroll 1
    for (int p = 0; p < 12; p++) {
        gru_full(XE, S1, RS, frG1, frC1, bg1r, bg1u, bc1c, l, col, [] {});
        gru_full(S1, S2, RS, frG2, frC2, bg2r, bg2u, bc2c, l, col, [&] {
            if (p < 11)
                do_xe(X, Win1, bin1, frXL, teo, XE, se_v, b * 12 + p + 1, n0, l, col);
        });
    }

    // head: h = relu(S2@Wo1+bo1) via MFMA into XE (packed), then y GEMV
    f32x4 accH[4];
    #pragma unroll
    for (int mt = 0; mt < 4; mt++) accH[mt] = (f32x4)0.0f;
    #pragma unroll
    for (int ks = 0; ks < 2; ks++) {
        bf16x8 bhi = ldfrag(frH + (ks * 2 + 0) * 512 + l * 8);
        bf16x8 blo = ldfrag(frH + (ks * 2 + 1) * 512 + l * 8);
        const int kk = ks * 32 + q * 8;
        #pragma unroll
        for (int mt = 0; mt < 4; mt++) {
            bf16x8 ahi, alo;
            lda_packed(S2, mt * 16 + n16, kk, ahi, alo);
            accH[mt] = MFMA(ahi, bhi, accH[mt]);
            accH[mt] = MFMA(alo, bhi, accH[mt]);
            accH[mt] = MFMA(ahi, blo, accH[mt]);
        }
    }
    const float bo1c = bo1[col];
    #pragma unroll
    for (int mt = 0; mt < 4; mt++)
        #pragma unroll
        for (int r = 0; r < 4; r++) {
            int tok = mt * 16 + q * 4 + r;
            XE[SW(tok, col)] = packf(fmaxf(accH[mt][r] + bo1c, 0.0f));
        }
    __syncthreads();
    // y: lane = token, wave owns q-cols 3w..3w+2
    const int swzt = SWZ(l);
    float y0 = bo2[3 * uw + 0], y1 = bo2[3 * uw + 1], y2 = bo2[3 * uw + 2];
    #pragma unroll
    for (int c = 0; c < 16; c++) {
        i32x4 d = *(const i32x4*)(XE + l * 64 + c * 4);
        const int j0 = (c * 4) ^ swzt;
        #pragma unroll
        for (int e = 0; e < 4; e++) {
            float hj = unpackf((u32)d[e]);
            int j = j0 + e;
            y0 = fmaf(hj, Wo2[j * 12 + 3 * uw + 0], y0);
            y1 = fmaf(hj, Wo2[j * 12 + 3 * uw + 1], y1);
            y2 = fmaf(hj, Wo2[j * 12 + 3 * uw + 2], y2);
        }
    }
    out[(b * 12 + 3 * uw + 0) * NB + n0 + l] = y0;
    out[(b * 12 + 3 * uw + 1) * NB + n0 + l] = y1;
    out[(b * 12 + 3 * uw + 2) * NB + n0 + l] = y2;
}

extern "C" void kernel_launch(void* const* d_in, const int* in_sizes, int n_in,
                              void* d_out, int out_size, void* d_ws, size_t ws_size,
                              hipStream_t stream) {
    const float* X    = (const float*)d_in[0];
    // d_in[1]=ZC, d_in[2]=ZF unused by the reference
    const float* SE   = (const float*)d_in[3];
    const float* Wse1 = (const float*)d_in[4];
    const float* bse1 = (const float*)d_in[5];
    const float* Wse2 = (const float*)d_in[6];
    const float* bse2 = (const float*)d_in[7];
    const float* Wte1 = (const float*)d_in[8];
    const float* bte1 = (const float*)d_in[9];
    const float* Wte2 = (const float*)d_in[10];
    const float* bte2 = (const float*)d_in[11];
    const float* Win1 = (const float*)d_in[12];
    const float* bin1 = (const float*)d_in[13];
    const float* Win2 = (const float*)d_in[14];
    const float* bin2 = (const float*)d_in[15];
    const float* Wg1  = (const float*)d_in[16];
    const float* bg1  = (const float*)d_in[17];
    const float* Wc1  = (const float*)d_in[18];
    const float* bc1  = (const float*)d_in[19];
    const float* Wg2  = (const float*)d_in[20];
    const float* bg2  = (const float*)d_in[21];
    const float* Wc2  = (const float*)d_in[22];
    const float* bc2  = (const float*)d_in[23];
    const float* Wo1  = (const float*)d_in[24];
    const float* bo1  = (const float*)d_in[25];
    const float* Wo2  = (const float*)d_in[26];
    const float* bo2  = (const float*)d_in[27];
    const int*   TE   = (const int*)d_in[28];

    float* ws = (float*)d_ws;                  // 172032 floats = 688 KB
    u16* fr = (u16*)ws;
    float* seB = ws + 57344;
    float* teo = ws + 122880;
    float* out = (float*)d_out;

    prep_gates<<<16, 256, 0, stream>>>(Wg1, Wg2, fr);
    prep_cand<<<8, 256, 0, stream>>>(Wc1, Wc2, fr);
    prep_small<<<4, 256, 0, stream>>>(Win2, Wo1, fr);
    prep_se<<<1024, 64, 0, stream>>>(SE, Wse1, bse1, Wse2, bse2, bin2, seB);
    prep_te<<<768, 64, 0, stream>>>(TE, Wte1, bte1, Wte2, bte2, teo);
    gman_main<<<1024, 256, 0, stream>>>(X, ws, Win1, bin1, bg1, bc1, bg2, bc2,
                                        bo1, Wo2, bo2, out);
}

// Round 13
// 540.742 us; speedup vs baseline: 1.4397x; 1.1648x over previous
//
#include <hip/hip_runtime.h>

// GMAN pipeline, fully fused, MFMA edition. support = I -> per-block token GEMMs.
// B=64, P=Q=12, N=1024, D=64. Output [B,Q,N] fp32.
//
// R24 = main kernel reverted to R20 VERBATIM (467us dispatch, no spill) +
// all five prep kernels fused into ONE launch.
// Evidence trail:
//  - R23: xe-fold into gru2's barrier region spilled (+62MB WRITE) -> 576us.
//    Scheduler interleaves freely within barrier bounds; source position and
//    sched_barrier both ineffective (R22). xe-fold CLOSED. R20 is the local
//    optimum under {128 regs, 8 waves/CU, 4+1 barriers, packed format}.
//  - Ledger: R20 total dur 545.9us vs main dispatch 467us -> ~79us is the 5
//    serial prep launches (~10us gap each + tiny work). Fusing them to one
//    kernel (block-uniform dispatch on blockIdx range; se/te do 4 rows per
//    256-thread block) cuts 4 launch gaps.
// Tripwires: gman_main counters must match R20 exactly (WRITE ~126MB,
// VGPR 128); total dur ~500-515us.

#define NB 1024

typedef float f32x4 __attribute__((ext_vector_type(4)));
typedef __bf16 bf16x8 __attribute__((ext_vector_type(8)));
typedef int i32x4 __attribute__((ext_vector_type(4)));
typedef unsigned int u32;
typedef unsigned short u16;

#define MFMA(a, b, c) __builtin_amdgcn_mfma_f32_16x16x32_bf16(a, b, c, 0, 0, 0)

__device__ __forceinline__ float fexp(float x) {
    return __builtin_amdgcn_exp2f(x * 1.44269504088896341f);
}
__device__ __forceinline__ float fsigmoid(float x) {
    return __builtin_amdgcn_rcpf(1.0f + fexp(-x));
}
__device__ __forceinline__ float ftanh(float x) {
    return 1.0f - 2.0f * __builtin_amdgcn_rcpf(1.0f + fexp(2.0f * x));
}

// pack fp32 -> {bf16 hi | bf16 lo} in one dword (truncation split)
__device__ __forceinline__ u32 packf(float v) {
    u32 u = __builtin_bit_cast(u32, v);
    u32 hb = u & 0xFFFF0000u;
    float lo = v - __builtin_bit_cast(float, hb);
    return hb | (__builtin_bit_cast(u32, lo) >> 16);
}
__device__ __forceinline__ float unpackf(u32 u) {
    return __builtin_bit_cast(float, u & 0xFFFF0000u)
         + __builtin_bit_cast(float, u << 16);
}

__device__ __forceinline__ bf16x8 ldfrag(const u16* p) {
    i32x4 t = *(const i32x4*)p;
    return __builtin_bit_cast(bf16x8, t);
}
// fragment load from an LDS-staged table (ds_read_b128)
__device__ __forceinline__ bf16x8 ldfragL(const u32* p) {
    i32x4 t = *(const i32x4*)p;
    return __builtin_bit_cast(bf16x8, t);
}
__device__ __forceinline__ void split8(f32x4 a0, f32x4 a1, bf16x8& hi, bf16x8& lo) {
    #pragma unroll
    for (int i = 0; i < 4; i++) {
        __bf16 h0 = (__bf16)a0[i]; hi[i] = h0;     lo[i] = (__bf16)(a0[i] - (float)h0);
        __bf16 h1 = (__bf16)a1[i]; hi[4 + i] = h1; lo[4 + i] = (__bf16)(a1[i] - (float)h1);
    }
}

// swizzle: xor k bits 2..4 by t bits; k bits 0-1 intact -> 4-dword windows legal
#define SWZ(t) ((((t) & 3) << 3) ^ ((t) & 4) ^ (((t) & 8) << 1))
#define SW(t, k) ((t) * 64 + ((k) ^ SWZ(t)))

// read packed A-frag: 8 consecutive k from swizzled row m, extract hi/lo via v_perm
__device__ __forceinline__ void lda_packed(const u32* __restrict__ src, int m, int kk,
                                           bf16x8& hi, bf16x8& lo) {
    const int sk = kk ^ SWZ(m);
    i32x4 d0 = *(const i32x4*)(src + m * 64 + sk);
    i32x4 d1 = *(const i32x4*)(src + m * 64 + (sk ^ 4));
    i32x4 h, L;
    h[0] = (int)__builtin_amdgcn_perm((u32)d0[1], (u32)d0[0], 0x07060302u);
    h[1] = (int)__builtin_amdgcn_perm((u32)d0[3], (u32)d0[2], 0x07060302u);
    h[2] = (int)__builtin_amdgcn_perm((u32)d1[1], (u32)d1[0], 0x07060302u);
    h[3] = (int)__builtin_amdgcn_perm((u32)d1[3], (u32)d1[2], 0x07060302u);
    L[0] = (int)__builtin_amdgcn_perm((u32)d0[1], (u32)d0[0], 0x05040100u);
    L[1] = (int)__builtin_amdgcn_perm((u32)d0[3], (u32)d0[2], 0x05040100u);
    L[2] = (int)__builtin_amdgcn_perm((u32)d1[1], (u32)d1[0], 0x05040100u);
    L[3] = (int)__builtin_amdgcn_perm((u32)d1[3], (u32)d1[2], 0x05040100u);
    hi = __builtin_bit_cast(bf16x8, h);
    lo = __builtin_bit_cast(bf16x8, L);
}

// ---------------- ws layout (dwords) ----------------
// 0      FR_G1 [wq][nt][ks][half][lane][8bf16] 16384 dw ; 16384 FR_G2
// 32768  FR_C1 [wq][ks][half][lane][8] 8192 dw ; 40960 FR_C2
// 49152  FR_XE Win2 ; 53248 FR_HD Wo1
// 57344  seB [nb(16)][w(4)][lane(64)][16] fp32 (b_in2 folded)  65536 dw
// 122880 teo [768][64] fp32

__device__ __forceinline__ void wsplit(float v, u16* dhi, u16* dlo) {
    __bf16 h = (__bf16)v;
    __bf16 l = (__bf16)(v - (float)h);
    *dhi = __builtin_bit_cast(u16, h);
    *dlo = __builtin_bit_cast(u16, l);
}

// ONE fused prep kernel. Branch on blockIdx range (block-uniform -> barriers
// legal). Blocks: [0,16) gates, [16,24) cand, [24,28) small,
// [28,284) se (4 rows/block), [284,476) te (4 rows/block). 256 threads.
__global__ void prep_all(
    const float* __restrict__ Wg1, const float* __restrict__ Wg2,
    const float* __restrict__ Wc1, const float* __restrict__ Wc2,
    const float* __restrict__ Win2, const float* __restrict__ Wo1,
    const float* __restrict__ SE, const float* __restrict__ Wse1,
    const float* __restrict__ bse1, const float* __restrict__ Wse2,
    const float* __restrict__ bse2, const float* __restrict__ bin2,
    const int* __restrict__ TE, const float* __restrict__ Wte1,
    const float* __restrict__ bte1, const float* __restrict__ Wte2,
    const float* __restrict__ bte2,
    u16* __restrict__ fr, float* __restrict__ seB, float* __restrict__ teo) {
    __shared__ float hsh[4][64];
    const int bid = blockIdx.x, tid = threadIdx.x;
    if (bid < 16) {                       // ---- gates
        int i = bid * 256 + tid;          // [0, 4096)
        int layer = i >> 11, r = i & 2047;
        int w = r >> 9; r &= 511; int nt = r >> 8; r &= 255;
        int ks = r >> 6; int lane = r & 63;
        const float* Wg = layer ? Wg2 : Wg1;
        int n = lane & 15, q = lane >> 4;
        int col = nt ? (64 + w * 16 + n) : (w * 16 + n);
        u16* dst = fr + layer * 32768 + (((w * 2 + nt) * 4 + ks) * 2) * 512 + lane * 8;
        #pragma unroll
        for (int j = 0; j < 8; j++) {
            int k = ks * 32 + q * 8 + j;
            float v = Wg[k * 128 + col] + Wg[(k + 128) * 128 + col];
            wsplit(v, dst + j, dst + 512 + j);
        }
    } else if (bid < 24) {                // ---- cand
        int i = (bid - 16) * 256 + tid;   // [0, 2048)
        int layer = i >> 10, r = i & 1023;
        int w = r >> 8; r &= 255; int ks = r >> 6; int lane = r & 63;
        const float* Wc = layer ? Wc2 : Wc1;
        int n = lane & 15, q = lane >> 4;
        int col = w * 16 + n;
        u16* dst = fr + 65536 + layer * 16384 + ((w * 4 + ks) * 2) * 512 + lane * 8;
        #pragma unroll
        for (int j = 0; j < 8; j++) {
            int k = ks * 32 + q * 8 + j;
            float v = Wc[k * 64 + col] + Wc[(k + 128) * 64 + col];
            wsplit(v, dst + j, dst + 512 + j);
        }
    } else if (bid < 28) {                // ---- small (Win2 / Wo1)
        int i = (bid - 24) * 256 + tid;   // [0, 1024)
        int kind = i >> 9, r = i & 511;
        int w = r >> 7; r &= 127; int ks = r >> 6; int lane = r & 63;
        const float* W = kind ? Wo1 : Win2;
        int n = lane & 15, q = lane >> 4;
        int col = w * 16 + n;
        u16* dst = fr + 98304 + kind * 8192 + ((w * 2 + ks) * 2) * 512 + lane * 8;
        #pragma unroll
        for (int j = 0; j < 8; j++) {
            int k = ks * 32 + q * 8 + j;
            float v = W[k * 64 + col];
            wsplit(v, dst + j, dst + 512 + j);
        }
    } else if (bid < 284) {               // ---- se: 4 rows per block
        int sb = tid >> 6, d = tid & 63;
        int n = (bid - 28) * 4 + sb;      // [0, 1024)
        float acc = bse1[d];
        for (int k = 0; k < 64; k++) acc = fmaf(SE[n * 64 + k], Wse1[k * 64 + d], acc);
        hsh[sb][d] = fmaxf(acc, 0.0f);
        __syncthreads();
        float acc2 = bse2[d];
        for (int k = 0; k < 64; k++) acc2 = fmaf(hsh[sb][k], Wse2[k * 64 + d], acc2);
        int nb = n >> 6, tok = n & 63;
        int mt = tok >> 4, q = (tok >> 2) & 3, r = tok & 3;
        int w = d >> 4, n16 = d & 15;
        seB[(((nb * 4 + w) * 64) + q * 16 + n16) * 16 + mt * 4 + r] = acc2 + bin2[d];
    } else {                              // ---- te: 4 rows per block
        int sb = tid >> 6, d = tid & 63;
        int bp = (bid - 284) * 4 + sb;    // [0, 768)
        int b = bp / 12, p = bp - b * 12;
        int dow = TE[(b * 24 + p) * 2 + 0];
        int tod = TE[(b * 24 + p) * 2 + 1];
        float v = Wte1[dow * 64 + d] + Wte1[(7 + tod) * 64 + d] + bte1[d];
        hsh[sb][d] = fmaxf(v, 0.0f);
        __syncthreads();
        float acc = bte2[d];
        for (int k = 0; k < 64; k++) acc = fmaf(hsh[sb][k], Wte2[k * 64 + d], acc);
        teo[bp * 64 + d] = acc;
    }
}

// full GRU step. Wave owns cols [16w,16w+16). Gate + cand fragments streamed
// from ws (L2-resident; remat beats spill at the 128-reg budget). RS is a
// SEPARATE buffer (alias is spill-bait: R19). No soldv (R15 lesson).
__device__ __forceinline__ void gru_full(
    const u32* __restrict__ XIN, u32* __restrict__ S, u32* __restrict__ RS,
    const u16* __restrict__ frG, const u16* __restrict__ frC,
    float bgr, float bgu, float bcc, int l, int col) {
    const int n16 = l & 15, q = l >> 4;
    f32x4 accR[4], accU[4], accC[4];
    #pragma unroll
    for (int mt = 0; mt < 4; mt++) {
        accR[mt] = (f32x4)0.0f; accU[mt] = (f32x4)0.0f; accC[mt] = (f32x4)0.0f;
    }
    // phase 1: ks 0..1 (XIN K-half): one A-frag feeds R+U+C
    #pragma unroll
    for (int ks = 0; ks < 2; ks++) {
        bf16x8 gRh = ldfrag(frG + (ks * 2 + 0) * 512 + l * 8);
        bf16x8 gRl = ldfrag(frG + (ks * 2 + 1) * 512 + l * 8);
        bf16x8 gUh = ldfrag(frG + (8 + ks * 2 + 0) * 512 + l * 8);
        bf16x8 gUl = ldfrag(frG + (8 + ks * 2 + 1) * 512 + l * 8);
        bf16x8 bhiC = ldfrag(frC + (ks * 2 + 0) * 512 + l * 8);
        bf16x8 bloC = ldfrag(frC + (ks * 2 + 1) * 512 + l * 8);
        const int kk = ks * 32 + q * 8;
        #pragma unroll
        for (int mt = 0; mt < 4; mt++) {
            bf16x8 ahi, alo;
            lda_packed(XIN, mt * 16 + n16, kk, ahi, alo);
            accR[mt] = MFMA(ahi, gRh, accR[mt]);
            accR[mt] = MFMA(alo, gRh, accR[mt]);
            accR[mt] = MFMA(ahi, gRl, accR[mt]);
            accU[mt] = MFMA(ahi, gUh, accU[mt]);
            accU[mt] = MFMA(alo, gUh, accU[mt]);
            accU[mt] = MFMA(ahi, gUl, accU[mt]);
            accC[mt] = MFMA(ahi, bhiC, accC[mt]);
            accC[mt] = MFMA(alo, bhiC, accC[mt]);
            accC[mt] = MFMA(ahi, bloC, accC[mt]);
        }
    }
    // phase 2: ks 2..3 (S K-half): gates only
    #pragma unroll
    for (int ks = 2; ks < 4; ks++) {
        bf16x8 gRh = ldfrag(frG + (ks * 2 + 0) * 512 + l * 8);
        bf16x8 gRl = ldfrag(frG + (ks * 2 + 1) * 512 + l * 8);
        bf16x8 gUh = ldfrag(frG + (8 + ks * 2 + 0) * 512 + l * 8);
        bf16x8 gUl = ldfrag(frG + (8 + ks * 2 + 1) * 512 + l * 8);
        const int kk = (ks - 2) * 32 + q * 8;
        #pragma unroll
        for (int mt = 0; mt < 4; mt++) {
            bf16x8 ahi, alo;
            lda_packed(S, mt * 16 + n16, kk, ahi, alo);
            accR[mt] = MFMA(ahi, gRh, accR[mt]);
            accR[mt] = MFMA(alo, gRh, accR[mt]);
            accR[mt] = MFMA(ahi, gRl, accR[mt]);
            accU[mt] = MFMA(ahi, gUh, accU[mt]);
            accU[mt] = MFMA(alo, gUh, accU[mt]);
            accU[mt] = MFMA(ahi, gUl, accU[mt]);
        }
    }
    // rs = sigmoid(r) * s (RS separate buffer -> no barrier needed first)
    #pragma unroll
    for (int mt = 0; mt < 4; mt++)
        #pragma unroll
        for (int r = 0; r < 4; r++) {
            int tok = mt * 16 + q * 4 + r;
            int a = SW(tok, col);
            RS[a] = packf(fsigmoid(accR[mt][r] + bgr) * unpackf(S[a]));
        }
    __syncthreads();   // rs visible
    // cand ks 2..3 (RS K-half)
    #pragma unroll
    for (int ks = 2; ks < 4; ks++) {
        bf16x8 bhi = ldfrag(frC + (ks * 2 + 0) * 512 + l * 8);
        bf16x8 blo = ldfrag(frC + (ks * 2 + 1) * 512 + l * 8);
        const int kk = (ks - 2) * 32 + q * 8;
        #pragma unroll
        for (int mt = 0; mt < 4; mt++) {
            bf16x8 ahi, alo;
            lda_packed(RS, mt * 16 + n16, kk, ahi, alo);
            accC[mt] = MFMA(ahi, bhi, accC[mt]);
            accC[mt] = MFMA(alo, bhi, accC[mt]);
            accC[mt] = MFMA(ahi, blo, accC[mt]);
        }
    }
    // state update (sold re-read from LDS: same thread, same address)
    #pragma unroll
    for (int mt = 0; mt < 4; mt++)
        #pragma unroll
        for (int r = 0; r < 4; r++) {
            int tok = mt * 16 + q * 4 + r;
            int a = SW(tok, col);
            float u = fsigmoid(accU[mt][r] + bgu);
            float cnd = ftanh(accC[mt][r] + bcc);
            float sold = unpackf(S[a]);
            S[a] = packf(u * sold + (1.0f - u) * cnd);
        }
    __syncthreads();   // state visible; RS reads done
}

__global__ __launch_bounds__(256, 2) void gman_main(
    const float* __restrict__ X, const float* __restrict__ ws,
    const float* __restrict__ Win1, const float* __restrict__ bin1,
    const float* __restrict__ bg1, const float* __restrict__ bc1,
    const float* __restrict__ bg2, const float* __restrict__ bc2,
    const float* __restrict__ bo1, const float* __restrict__ Wo2,
    const float* __restrict__ bo2, float* __restrict__ out) {
    __shared__ u32 XE[4096], S1[4096], S2[4096], RS[4096];   // 64 KB
    __shared__ u32 FRX[4096];                                // +16 KB Win2 frags
    // total 80 KB; 2 blocks/CU

    const int tid = threadIdx.x;
    const int l = tid & 63;
    const int w = tid >> 6;
    const int uw = __builtin_amdgcn_readfirstlane(w);
    const int n16 = l & 15, q = l >> 4;
    const int col = uw * 16 + n16;
    const int b = blockIdx.x >> 4;
    const int nb = blockIdx.x & 15;
    const int n0 = nb << 6;

    const u16* frU = (const u16*)ws;
    const u16* frG1 = frU + uw * 8192;
    const u16* frG2 = frU + 32768 + uw * 8192;
    const u16* frC1 = frU + 65536 + uw * 4096;
    const u16* frC2 = frU + 81920 + uw * 4096;
    const u16* frH  = frU + 106496 + uw * 2048;
    const float* seQ = ws + 57344 + (((nb * 4 + uw) * 64) + l) * 16;
    const float* teo = ws + 122880;

    // stage Win2 frag table (FR_XE, dwords 49152..53247) into LDS
    const u32* frXsrc = (const u32*)ws + 49152;
    #pragma unroll
    for (int i = 0; i < 16; i++) FRX[tid + i * 256] = frXsrc[tid + i * 256];
    const u32* frXL = FRX + uw * 1024;   // per-wave quarter, dword units

    #pragma unroll
    for (int i = 0; i < 16; i++) { S1[tid + i * 256] = 0u; S2[tid + i * 256] = 0u; }

    f32x4 se_v[4];
    #pragma unroll
    for (int mt = 0; mt < 4; mt++) se_v[mt] = *(const f32x4*)(seQ + mt * 4);
    const float bg1r = bg1[col], bg1u = bg1[64 + col], bc1c = bc1[col];
    const float bg2r = bg2[col], bg2u = bg2[64 + col], bc2c = bc2[col];

    __syncthreads();   // FRX + S-init visible before first use

    #pragma unroll 1
    for (int p = 0; p < 12; p++) {
        // raw x direct from global (L1-resident row; 4 values per thread)
        const float* xrow = X + (b * 12 + p) * NB + n0;
        float xm[4];
        #pragma unroll
        for (int mt = 0; mt < 4; mt++) xm[mt] = xrow[mt * 16 + n16];
        const float tev = teo[(b * 12 + p) * 64 + col];
        // xe GEMM: A = h1 = relu(x*Win1+bin1) built in regs, B = Win2 quarter (LDS)
        f32x4 accX[4];
        #pragma unroll
        for (int mt = 0; mt < 4; mt++) accX[mt] = (f32x4)0.0f;
        #pragma unroll
        for (int ks = 0; ks < 2; ks++) {
            const int k0 = ks * 32 + q * 8;
            f32x4 w1a = *(const f32x4*)(Win1 + k0), w1b = *(const f32x4*)(Win1 + k0 + 4);
            f32x4 b1a = *(const f32x4*)(bin1 + k0), b1b = *(const f32x4*)(bin1 + k0 + 4);
            bf16x8 bhi = ldfragL(frXL + (ks * 2 + 0) * 256 + l * 4);
            bf16x8 blo = ldfragL(frXL + (ks * 2 + 1) * 256 + l * 4);
            #pragma unroll
            for (int mt = 0; mt < 4; mt++) {
                f32x4 h0, h1v;
                #pragma unroll
                for (int i = 0; i < 4; i++) {
                    h0[i]  = fmaxf(fmaf(xm[mt], w1a[i], b1a[i]), 0.0f);
                    h1v[i] = fmaxf(fmaf(xm[mt], w1b[i], b1b[i]), 0.0f);
                }
                bf16x8 ahi, alo; split8(h0, h1v, ahi, alo);
                accX[mt] = MFMA(ahi, bhi, accX[mt]);
                accX[mt] = MFMA(alo, bhi, accX[mt]);
                accX[mt] = MFMA(ahi, blo, accX[mt]);
            }
        }
        // XE write safe without pre-barrier: last XE reads (gru1 phase 1 of
        // step p-1) retired before p-1's rs barrier.
        #pragma unroll
        for (int mt = 0; mt < 4; mt++)
            #pragma unroll
            for (int r = 0; r < 4; r++) {
                int tok = mt * 16 + q * 4 + r;
                XE[SW(tok, col)] = packf(accX[mt][r] + se_v[mt][r] + tev);
            }
        __syncthreads();   // XE complete

        gru_full(XE, S1, RS, frG1, frC1, bg1r, bg1u, bc1c, l, col);
        gru_full(S1, S2, RS, frG2, frC2, bg2r, bg2u, bc2c, l, col);
    }

    // head: h = relu(S2@Wo1+bo1) via MFMA into XE (packed), then y GEMV
    f32x4 accH[4];
    #pragma unroll
    for (int mt = 0; mt < 4; mt++) accH[mt] = (f32x4)0.0f;
    #pragma unroll
    for (int ks = 0; ks < 2; ks++) {
        bf16x8 bhi = ldfrag(frH + (ks * 2 + 0) * 512 + l * 8);
        bf16x8 blo = ldfrag(frH + (ks * 2 + 1) * 512 + l * 8);
        const int kk = ks * 32 + q * 8;
        #pragma unroll
        for (int mt = 0; mt < 4; mt++) {
            bf16x8 ahi, alo;
            lda_packed(S2, mt * 16 + n16, kk, ahi, alo);
            accH[mt] = MFMA(ahi, bhi, accH[mt]);
            accH[mt] = MFMA(alo, bhi, accH[mt]);
            accH[mt] = MFMA(ahi, blo, accH[mt]);
        }
    }
    const float bo1c = bo1[col];
    #pragma unroll
    for (int mt = 0; mt < 4; mt++)
        #pragma unroll
        for (int r = 0; r < 4; r++) {
            int tok = mt * 16 + q * 4 + r;
            XE[SW(tok, col)] = packf(fmaxf(accH[mt][r] + bo1c, 0.0f));
        }
    __syncthreads();
    // y: lane = token, wave owns q-cols 3w..3w+2
    const int swzt = SWZ(l);
    float y0 = bo2[3 * uw + 0], y1 = bo2[3 * uw + 1], y2 = bo2[3 * uw + 2];
    #pragma unroll
    for (int c = 0; c < 16; c++) {
        i32x4 d = *(const i32x4*)(XE + l * 64 + c * 4);
        const int j0 = (c * 4) ^ swzt;
        #pragma unroll
        for (int e = 0; e < 4; e++) {
            float hj = unpackf((u32)d[e]);
            int j = j0 + e;
            y0 = fmaf(hj, Wo2[j * 12 + 3 * uw + 0], y0);
            y1 = fmaf(hj, Wo2[j * 12 + 3 * uw + 1], y1);
            y2 = fmaf(hj, Wo2[j * 12 + 3 * uw + 2], y2);
        }
    }
    out[(b * 12 + 3 * uw + 0) * NB + n0 + l] = y0;
    out[(b * 12 + 3 * uw + 1) * NB + n0 + l] = y1;
    out[(b * 12 + 3 * uw + 2) * NB + n0 + l] = y2;
}

extern "C" void kernel_launch(void* const* d_in, const int* in_sizes, int n_in,
                              void* d_out, int out_size, void* d_ws, size_t ws_size,
                              hipStream_t stream) {
    const float* X    = (const float*)d_in[0];
    // d_in[1]=ZC, d_in[2]=ZF unused by the reference
    const float* SE   = (const float*)d_in[3];
    const float* Wse1 = (const float*)d_in[4];
    const float* bse1 = (const float*)d_in[5];
    const float* Wse2 = (const float*)d_in[6];
    const float* bse2 = (const float*)d_in[7];
    const float* Wte1 = (const float*)d_in[8];
    const float* bte1 = (const float*)d_in[9];
    const float* Wte2 = (const float*)d_in[10];
    const float* bte2 = (const float*)d_in[11];
    const float* Win1 = (const float*)d_in[12];
    const float* bin1 = (const float*)d_in[13];
    const float* Win2 = (const float*)d_in[14];
    const float* bin2 = (const float*)d_in[15];
    const float* Wg1  = (const float*)d_in[16];
    const float* bg1  = (const float*)d_in[17];
    const float* Wc1  = (const float*)d_in[18];
    const float* bc1  = (const float*)d_in[19];
    const float* Wg2  = (const float*)d_in[20];
    const float* bg2  = (const float*)d_in[21];
    const float* Wc2  = (const float*)d_in[22];
    const float* bc2  = (const float*)d_in[23];
    const float* Wo1  = (const float*)d_in[24];
    const float* bo1  = (const float*)d_in[25];
    const float* Wo2  = (const float*)d_in[26];
    const float* bo2  = (const float*)d_in[27];
    const int*   TE   = (const int*)d_in[28];

    float* ws = (float*)d_ws;                  // 172032 floats = 688 KB
    u16* fr = (u16*)ws;
    float* seB = ws + 57344;
    float* teo = ws + 122880;
    float* out = (float*)d_out;

    prep_all<<<476, 256, 0, stream>>>(Wg1, Wg2, Wc1, Wc2, Win2, Wo1,
                                      SE, Wse1, bse1, Wse2, bse2, bin2,
                                      TE, Wte1, bte1, Wte2, bte2,
                                      fr, seB, teo);
    gman_main<<<1024, 256, 0, stream>>>(X, ws, Win1, bin1, bg1, bc1, bg2, bc2,
                                        bo1, Wo2, bo2, out);
}